// Round 1
// baseline (6031.147 us; speedup 1.0000x reference)
//
#include <hip/hip_runtime.h>

// ---------------- problem constants (match reference) ----------------
#define NMOL   2048
#define BD     64
#define PITCH  65            // LDS row pitch (bank-conflict padding)
#define NROT_C 1000000
#define NN     4000000       // len(net_vals)
#define NREP_C 500000
#define ROT_LEN_C (2 + NROT_C * 3)

// ---------------- stage 1: net_vals = net_base; scatter x (last write wins) --
__global__ __launch_bounds__(256) void k_copy(const float4* __restrict__ src,
                                              float4* __restrict__ dst, int n4) {
    int i = blockIdx.x * blockDim.x + threadIdx.x;
    int stride = gridDim.x * blockDim.x;
    for (; i < n4; i += stride) dst[i] = src[i];
}

__global__ __launch_bounds__(256) void k_scat_init(const int* __restrict__ idx,
                                                   int* __restrict__ winner, int nx) {
    int i = blockIdx.x * blockDim.x + threadIdx.x;
    if (i < nx) winner[idx[i]] = -1;
}
__global__ __launch_bounds__(256) void k_scat_max(const int* __restrict__ idx,
                                                  int* __restrict__ winner, int nx) {
    int i = blockIdx.x * blockDim.x + threadIdx.x;
    if (i < nx) atomicMax(&winner[idx[i]], i);
}
__global__ __launch_bounds__(256) void k_scat_write(const int* __restrict__ idx,
                                                    const int* __restrict__ winner,
                                                    const float* __restrict__ x,
                                                    float* __restrict__ net, int nx) {
    int i = blockIdx.x * blockDim.x + threadIdx.x;
    if (i < nx && winner[idx[i]] == i) net[idx[i]] = x[i];
}

// ---------------- stage 2: rotations + oper gather ----------------
__global__ __launch_bounds__(256) void k_rot(const float* __restrict__ net,
                                             const int* __restrict__ rg,
                                             const float* __restrict__ rt,
                                             float* __restrict__ rot_out, int nrot) {
    int r = blockIdx.x * blockDim.x + threadIdx.x;
    if (r == 0) { rot_out[0] = 0.f; rot_out[1] = 1.f; }
    if (r >= nrot) return;
    int i0 = rg[3 * r], i1 = rg[3 * r + 1], i2 = rg[3 * r + 2];
    float v0 = net[i0], v1 = net[i1], v2 = net[i2];
    const float* T = rt + (size_t)r * 9;
    rot_out[2 + 3 * r + 0] = T[0] * v0 + T[1] * v1 + T[2] * v2;
    rot_out[2 + 3 * r + 1] = T[3] * v0 + T[4] * v1 + T[5] * v2;
    rot_out[2 + 3 * r + 2] = T[6] * v0 + T[7] * v1 + T[8] * v2;
}

__global__ __launch_bounds__(256) void k_oper(const float* __restrict__ rot_out,
                                              const int* __restrict__ og,
                                              float* __restrict__ H, int total) {
    int i = blockIdx.x * blockDim.x + threadIdx.x;
    if (i < total) H[i] = rot_out[og[i]];
}

// ---------------- stage 3: Fock assembly, one block per molecule ------------
__global__ __launch_bounds__(256) void k_fock(const float* __restrict__ S,
                                              const float* __restrict__ G,
                                              const float* __restrict__ rho,
                                              const float* __restrict__ qn,
                                              const float* __restrict__ H,
                                              float* __restrict__ F,
                                              float* __restrict__ Eelec) {
    __shared__ float Ssh[BD * PITCH];
    __shared__ float part[BD * 4];
    __shared__ float dQ[BD], ep[BD];
    int m = blockIdx.x, tid = threadIdx.x;
    size_t base = (size_t)m * BD * BD;
    int i = tid >> 2, jq = tid & 3;
    int j0 = jq * 16;

    float acc = 0.f;
#pragma unroll
    for (int jj = 0; jj < 16; ++jj) {
        int j = j0 + jj;
        float sv = S[base + i * BD + j];
        float rv = rho[base + i * BD + j];
        Ssh[i * PITCH + j] = sv;
        acc += sv * rv;
    }
    part[i * 4 + jq] = acc;
    __syncthreads();
    if (tid < BD)
        dQ[tid] = qn[(size_t)m * BD + tid] -
                  (part[tid * 4] + part[tid * 4 + 1] + part[tid * 4 + 2] + part[tid * 4 + 3]);
    __syncthreads();

    float acc2 = 0.f;
#pragma unroll
    for (int jj = 0; jj < 16; ++jj) {
        int j = j0 + jj;
        acc2 += G[base + i * BD + j] * dQ[j];
    }
    part[i * 4 + jq] = acc2;
    __syncthreads();
    if (tid < BD) {
        float e = part[tid * 4] + part[tid * 4 + 1] + part[tid * 4 + 2] + part[tid * 4 + 3];
        ep[tid] = e;
        float v = dQ[tid] * e;
        for (int off = 32; off > 0; off >>= 1) v += __shfl_down(v, off, 64);
        if (tid == 0) Eelec[m] = 0.5f * v;      // ener2; k_eig adds ener1 later
    }
    __syncthreads();

#pragma unroll
    for (int u = 0; u < 16; ++u) {
        int idx = tid + 256 * u;
        int i2 = idx >> 6, j2 = idx & 63;
        F[base + idx] = H[base + idx] - 0.5f * Ssh[i2 * PITCH + j2] * (ep[i2] + ep[j2]);
    }
}

// ---------------- stage 4: Erep segment sum (deterministic, no atomics) -----
__global__ __launch_bounds__(64) void k_erep(const float* __restrict__ net,
                                             const int* __restrict__ rg,
                                             const int* __restrict__ seg,
                                             float* __restrict__ Erep, int nrep) {
    int m = blockIdx.x, lane = threadIdx.x;
    int lo = 0, hi = nrep;
    while (lo < hi) { int mid = (lo + hi) >> 1; if (seg[mid] < m) lo = mid + 1; else hi = mid; }
    int start = lo;
    hi = nrep;
    while (lo < hi) { int mid = (lo + hi) >> 1; if (seg[mid] < m + 1) lo = mid + 1; else hi = mid; }
    int end = lo;
    float s = 0.f;
    for (int k = start + lane; k < end; k += 64) s += net[rg[k]];
    for (int off = 32; off > 0; off >>= 1) s += __shfl_down(s, off, 64);
    if (lane == 0) Erep[m] = s;
}

// ---------------- stage 5: eigh (parallel Jacobi) + rho/energies ------------
#define MAXSWEEP 16
__global__ __launch_bounds__(256) void k_eig(const float* __restrict__ F,
                                             const float* __restrict__ phiS,
                                             const float* __restrict__ Hws,
                                             float* __restrict__ Eorb,
                                             float* __restrict__ rho_out,
                                             float* __restrict__ Eelec) {
    __shared__ float P[BD * PITCH];   // phiS
    __shared__ float A[BD * PITCH];   // work matrix
    __shared__ float V[BD * PITCH];   // eigenvectors
    __shared__ float cs[32], sn[32];
    __shared__ int   pp[32], qq[32];
    __shared__ float evals[BD];
    __shared__ int   perm[BD];
    __shared__ float red[256];

    int m = blockIdx.x, tid = threadIdx.x;
    size_t base = (size_t)m * BD * BD;

    // load phiS -> P, F -> V
    for (int u = 0; u < 16; ++u) {
        int idx = tid + 256 * u; int i = idx >> 6, j = idx & 63;
        P[i * PITCH + j] = phiS[base + idx];
        V[i * PITCH + j] = F[base + idx];
    }
    __syncthreads();

    // A = F @ P    (T)
    for (int u = 0; u < 16; ++u) {
        int idx = tid + 256 * u; int i = idx >> 6, j = idx & 63;
        float a = 0.f;
        for (int k = 0; k < BD; ++k) a += V[i * PITCH + k] * P[k * PITCH + j];
        A[i * PITCH + j] = a;
    }
    __syncthreads();

    // V = P^T @ A  (fockp)
    for (int u = 0; u < 16; ++u) {
        int idx = tid + 256 * u; int i = idx >> 6, j = idx & 63;
        float a = 0.f;
        for (int k = 0; k < BD; ++k) a += P[k * PITCH + i] * A[k * PITCH + j];
        V[i * PITCH + j] = a;
    }
    __syncthreads();

    // A = sym(fockp) = 0.5*(V + V^T)  (jnp.linalg.eigh symmetrize semantics)
    float s2 = 0.f;
    for (int u = 0; u < 16; ++u) {
        int idx = tid + 256 * u; int i = idx >> 6, j = idx & 63;
        float av = 0.5f * (V[i * PITCH + j] + V[j * PITCH + i]);
        A[i * PITCH + j] = av;
        s2 += av * av;
    }
    red[tid] = s2;
    __syncthreads();
    for (int st = 128; st > 0; st >>= 1) { if (tid < st) red[tid] += red[tid + st]; __syncthreads(); }
    float tol = fmaxf(red[0] * 1e-12f, 1e-30f);
    __syncthreads();

    // V = I
    for (int u = 0; u < 16; ++u) {
        int idx = tid + 256 * u; int i = idx >> 6, j = idx & 63;
        V[i * PITCH + j] = (i == j) ? 1.f : 0.f;
    }
    __syncthreads();

    // parallel cyclic Jacobi: 63 rounds of 32 disjoint pairs per sweep
    for (int sweep = 0; sweep < MAXSWEEP; ++sweep) {
        for (int r = 0; r < 63; ++r) {
            if (tid < 32) {
                int p, q;
                if (tid == 0) { p = 63; q = r; }
                else { p = (r + tid) % 63; q = (r + 63 - tid) % 63; }
                float app = A[p * PITCH + p], aqq = A[q * PITCH + q], apq = A[p * PITCH + q];
                float c = 1.f, s = 0.f;
                if (fabsf(apq) > 1e-36f) {
                    float theta = (aqq - app) / (2.f * apq);
                    float t = 1.f / (fabsf(theta) + sqrtf(theta * theta + 1.f));
                    if (theta < 0.f) t = -t;
                    c = 1.f / sqrtf(t * t + 1.f);
                    s = t * c;
                }
                pp[tid] = p; qq[tid] = q; cs[tid] = c; sn[tid] = s;
            }
            __syncthreads();
            int pr = tid >> 3;
            int p = pp[pr], q = qq[pr];
            float c = cs[pr], s = sn[pr];
            int c0 = tid & 7;
            // row update: B = J^T A
#pragma unroll
            for (int j = 0; j < 8; ++j) {
                int col = c0 + 8 * j;
                float a = A[p * PITCH + col], b = A[q * PITCH + col];
                A[p * PITCH + col] = c * a - s * b;
                A[q * PITCH + col] = s * a + c * b;
            }
            __syncthreads();
            // col update: A = B J, V = V J
#pragma unroll
            for (int j = 0; j < 8; ++j) {
                int row = c0 + 8 * j;
                float a = A[row * PITCH + p], b = A[row * PITCH + q];
                A[row * PITCH + p] = c * a - s * b;
                A[row * PITCH + q] = s * a + c * b;
                float va = V[row * PITCH + p], vb = V[row * PITCH + q];
                V[row * PITCH + p] = c * va - s * vb;
                V[row * PITCH + q] = s * va + c * vb;
            }
            __syncthreads();
        }
        // convergence: off-diagonal Frobenius^2
        float o2 = 0.f;
        for (int u = 0; u < 16; ++u) {
            int idx = tid + 256 * u; int i = idx >> 6, j = idx & 63;
            if (i != j) { float v = A[i * PITCH + j]; o2 += v * v; }
        }
        red[tid] = o2;
        __syncthreads();
        for (int st = 128; st > 0; st >>= 1) { if (tid < st) red[tid] += red[tid + st]; __syncthreads(); }
        if (red[0] <= tol) break;
        __syncthreads();
    }
    __syncthreads();

    // eigenvalues, ascending rank (stable), write Eorb
    if (tid < BD) evals[tid] = A[tid * PITCH + tid];
    __syncthreads();
    if (tid < BD) {
        float lam = evals[tid];
        int rnk = 0;
        for (int j2 = 0; j2 < BD; ++j2) {
            float o = evals[j2];
            rnk += (o < lam) || (o == lam && j2 < tid);
        }
        perm[rnk] = tid;
        Eorb[(size_t)m * BD + rnk] = lam;
    }
    __syncthreads();

    // orb_occ = phiS @ V[:, perm[0..31]]  -> into A[:, 0..31]
    for (int u = 0; u < 8; ++u) {
        int idx = tid + 256 * u; int i = idx >> 5, j = idx & 31;
        int pj = perm[j];
        float a = 0.f;
        for (int k = 0; k < BD; ++k) a += P[i * PITCH + k] * V[k * PITCH + pj];
        A[i * PITCH + j] = a;
    }
    __syncthreads();

    // rho = 2 * orb_occ @ orb_occ^T ; ener1 = sum(rho * H)
    float accE = 0.f;
    for (int u = 0; u < 16; ++u) {
        int idx = tid + 256 * u; int i = idx >> 6, j = idx & 63;
        float rv = 0.f;
        for (int t = 0; t < 32; ++t) rv += A[i * PITCH + t] * A[j * PITCH + t];
        rv *= 2.f;
        rho_out[base + idx] = rv;
        accE += rv * Hws[base + idx];
    }
    red[tid] = accE;
    __syncthreads();
    for (int st = 128; st > 0; st >>= 1) { if (tid < st) red[tid] += red[tid + st]; __syncthreads(); }
    if (tid == 0) Eelec[m] = Eelec[m] + red[0];
}

// ---------------- launcher ----------------
extern "C" void kernel_launch(void* const* d_in, const int* in_sizes, int n_in,
                              void* d_out, int out_size, void* d_ws, size_t ws_size,
                              hipStream_t stream) {
    const float* x           = (const float*)d_in[0];
    const float* net_base    = (const float*)d_in[1];
    const float* rot_tensors = (const float*)d_in[2];
    const float* S           = (const float*)d_in[3];
    const float* G           = (const float*)d_in[4];
    const float* rho_in      = (const float*)d_in[5];
    const float* phiS        = (const float*)d_in[6];
    const float* qn          = (const float*)d_in[7];
    // d_in[8] occ_mask: constant (col < 32), folded into k_eig
    const int* scatter_idx   = (const int*)d_in[9];
    const int* rot_gather    = (const int*)d_in[10];
    const int* oper_gather   = (const int*)d_in[11];
    const int* rep_gather    = (const int*)d_in[12];
    const int* rep_seg       = (const int*)d_in[13];

    float* out   = (float*)d_out;
    float* oEelec = out;                               // NMOL
    float* oErep  = oEelec + NMOL;                     // NMOL
    float* oEorb  = oErep + NMOL;                      // NMOL*64
    float* oRho   = oEorb + (size_t)NMOL * BD;         // NMOL*64*64
    float* oF     = oRho + (size_t)NMOL * BD * BD;     // NMOL*64*64

    // workspace layout (~61.6 MB):
    float* ws_net = (float*)d_ws;                      // NN floats
    float* ws_rot = ws_net + NN;                       // ROT_LEN floats (+pad)
    float* ws_H   = ws_rot + 3000004;                  // NMOL*64*64 floats
    int*   winner = (int*)ws_H;                        // alias (dead before H is written)

    int nx = in_sizes[0];
    int total_ops = NMOL * BD * BD;

    k_copy<<<2048, 256, 0, stream>>>((const float4*)net_base, (float4*)ws_net, NN / 4);
    int gb = (nx + 255) / 256;
    k_scat_init <<<gb, 256, 0, stream>>>(scatter_idx, winner, nx);
    k_scat_max  <<<gb, 256, 0, stream>>>(scatter_idx, winner, nx);
    k_scat_write<<<gb, 256, 0, stream>>>(scatter_idx, winner, x, ws_net, nx);
    k_rot<<<(NROT_C + 255) / 256, 256, 0, stream>>>(ws_net, rot_gather, rot_tensors, ws_rot, NROT_C);
    k_oper<<<(total_ops + 255) / 256, 256, 0, stream>>>(ws_rot, oper_gather, ws_H, total_ops);
    k_fock<<<NMOL, 256, 0, stream>>>(S, G, rho_in, qn, ws_H, oF, oEelec);
    k_erep<<<NMOL, 64, 0, stream>>>(ws_net, rep_gather, rep_seg, oErep, NREP_C);
    k_eig<<<NMOL, 256, 0, stream>>>(oF, phiS, ws_H, oEorb, oRho, oEelec);
}

// Round 2
// 3531.992 us; speedup vs baseline: 1.7076x; 1.7076x over previous
//
#include <hip/hip_runtime.h>

// ---------------- problem constants (match reference) ----------------
#define NMOL   2048
#define BD     64
#define PITCH  65            // LDS row pitch: bank = (row + col) % 32
#define NROT_C 1000000
#define NN     4000000       // len(net_vals)
#define NREP_C 500000
#define ROT_LEN_C (2 + NROT_C * 3)

// ---------------- stage 1: net_vals = net_base; scatter x (last write wins) --
__global__ __launch_bounds__(256) void k_copy(const float4* __restrict__ src,
                                              float4* __restrict__ dst, int n4) {
    int i = blockIdx.x * blockDim.x + threadIdx.x;
    int stride = gridDim.x * blockDim.x;
    for (; i < n4; i += stride) dst[i] = src[i];
}

__global__ __launch_bounds__(256) void k_scat_init(const int* __restrict__ idx,
                                                   int* __restrict__ winner, int nx) {
    int i = blockIdx.x * blockDim.x + threadIdx.x;
    if (i < nx) winner[idx[i]] = -1;
}
__global__ __launch_bounds__(256) void k_scat_max(const int* __restrict__ idx,
                                                  int* __restrict__ winner, int nx) {
    int i = blockIdx.x * blockDim.x + threadIdx.x;
    if (i < nx) atomicMax(&winner[idx[i]], i);
}
__global__ __launch_bounds__(256) void k_scat_write(const int* __restrict__ idx,
                                                    const int* __restrict__ winner,
                                                    const float* __restrict__ x,
                                                    float* __restrict__ net, int nx) {
    int i = blockIdx.x * blockDim.x + threadIdx.x;
    if (i < nx && winner[idx[i]] == i) net[idx[i]] = x[i];
}

// ---------------- stage 2: rotations + oper gather ----------------
__global__ __launch_bounds__(256) void k_rot(const float* __restrict__ net,
                                             const int* __restrict__ rg,
                                             const float* __restrict__ rt,
                                             float* __restrict__ rot_out, int nrot) {
    int r = blockIdx.x * blockDim.x + threadIdx.x;
    if (r == 0) { rot_out[0] = 0.f; rot_out[1] = 1.f; }
    if (r >= nrot) return;
    int i0 = rg[3 * r], i1 = rg[3 * r + 1], i2 = rg[3 * r + 2];
    float v0 = net[i0], v1 = net[i1], v2 = net[i2];
    const float* T = rt + (size_t)r * 9;
    rot_out[2 + 3 * r + 0] = T[0] * v0 + T[1] * v1 + T[2] * v2;
    rot_out[2 + 3 * r + 1] = T[3] * v0 + T[4] * v1 + T[5] * v2;
    rot_out[2 + 3 * r + 2] = T[6] * v0 + T[7] * v1 + T[8] * v2;
}

__global__ __launch_bounds__(256) void k_oper(const float* __restrict__ rot_out,
                                              const int* __restrict__ og,
                                              float* __restrict__ H, int total) {
    int i = blockIdx.x * blockDim.x + threadIdx.x;
    if (i < total) H[i] = rot_out[og[i]];
}

// ---------------- stage 3: Fock assembly, one block per molecule ------------
__global__ __launch_bounds__(256) void k_fock(const float* __restrict__ S,
                                              const float* __restrict__ G,
                                              const float* __restrict__ rho,
                                              const float* __restrict__ qn,
                                              const float* __restrict__ H,
                                              float* __restrict__ F,
                                              float* __restrict__ Eelec) {
    __shared__ float Ssh[BD * PITCH];
    __shared__ float part[BD * 4];
    __shared__ float dQ[BD], ep[BD];
    int m = blockIdx.x, tid = threadIdx.x;
    size_t base = (size_t)m * BD * BD;
    int i = tid >> 2, jq = tid & 3;
    int j0 = jq * 16;

    float acc = 0.f;
#pragma unroll
    for (int jj = 0; jj < 16; ++jj) {
        int j = j0 + jj;
        float sv = S[base + i * BD + j];
        float rv = rho[base + i * BD + j];
        Ssh[i * PITCH + j] = sv;
        acc += sv * rv;
    }
    part[i * 4 + jq] = acc;
    __syncthreads();
    if (tid < BD)
        dQ[tid] = qn[(size_t)m * BD + tid] -
                  (part[tid * 4] + part[tid * 4 + 1] + part[tid * 4 + 2] + part[tid * 4 + 3]);
    __syncthreads();

    float acc2 = 0.f;
#pragma unroll
    for (int jj = 0; jj < 16; ++jj) {
        int j = j0 + jj;
        acc2 += G[base + i * BD + j] * dQ[j];
    }
    part[i * 4 + jq] = acc2;
    __syncthreads();
    if (tid < BD) {
        float e = part[tid * 4] + part[tid * 4 + 1] + part[tid * 4 + 2] + part[tid * 4 + 3];
        ep[tid] = e;
        float v = dQ[tid] * e;
        for (int off = 32; off > 0; off >>= 1) v += __shfl_down(v, off, 64);
        if (tid == 0) Eelec[m] = 0.5f * v;      // ener2; k_eig adds ener1 later
    }
    __syncthreads();

#pragma unroll
    for (int u = 0; u < 16; ++u) {
        int idx = tid + 256 * u;
        int i2 = idx >> 6, j2 = idx & 63;
        F[base + idx] = H[base + idx] - 0.5f * Ssh[i2 * PITCH + j2] * (ep[i2] + ep[j2]);
    }
}

// ---------------- stage 4: Erep segment sum (deterministic, no atomics) -----
__global__ __launch_bounds__(64) void k_erep(const float* __restrict__ net,
                                             const int* __restrict__ rg,
                                             const int* __restrict__ seg,
                                             float* __restrict__ Erep, int nrep) {
    int m = blockIdx.x, lane = threadIdx.x;
    int lo = 0, hi = nrep;
    while (lo < hi) { int mid = (lo + hi) >> 1; if (seg[mid] < m) lo = mid + 1; else hi = mid; }
    int start = lo;
    hi = nrep;
    while (lo < hi) { int mid = (lo + hi) >> 1; if (seg[mid] < m + 1) lo = mid + 1; else hi = mid; }
    int end = lo;
    float s = 0.f;
    for (int k = start + lane; k < end; k += 64) s += net[rg[k]];
    for (int off = 32; off > 0; off >>= 1) s += __shfl_down(s, off, 64);
    if (lane == 0) Erep[m] = s;
}

// ---------------- stage 5: eigh (parallel Jacobi) + rho/energies ------------
// Pair->group permutation pi(g) = 4*(g&7) + (g>>3): within each wave the 8
// groups' p-values are spaced 4 apart mod 63, so their 8-bank access windows
// tile the 32 LDS banks exactly 2x (2-way aliasing is free on gfx950).
#define MAXSWEEP 10
__global__ __launch_bounds__(256) void k_eig(const float* __restrict__ F,
                                             const float* __restrict__ phiS,
                                             const float* __restrict__ Hws,
                                             float* __restrict__ Eorb,
                                             float* __restrict__ rho_out,
                                             float* __restrict__ Eelec) {
    __shared__ float P[BD * PITCH];   // phiS
    __shared__ float A[BD * PITCH];   // work matrix
    __shared__ float V[BD * PITCH];   // eigenvectors
    __shared__ float evals[BD];
    __shared__ int   perm[BD];
    __shared__ float red[256];

    int m = blockIdx.x, tid = threadIdx.x;
    size_t base = (size_t)m * BD * BD;

    // load phiS -> P, F -> V
    for (int u = 0; u < 16; ++u) {
        int idx = tid + 256 * u; int i = idx >> 6, j = idx & 63;
        P[i * PITCH + j] = phiS[base + idx];
        V[i * PITCH + j] = F[base + idx];
    }
    __syncthreads();

    // A = F @ P
    for (int u = 0; u < 16; ++u) {
        int idx = tid + 256 * u; int i = idx >> 6, j = idx & 63;
        float a = 0.f;
        for (int k = 0; k < BD; ++k) a += V[i * PITCH + k] * P[k * PITCH + j];
        A[i * PITCH + j] = a;
    }
    __syncthreads();

    // V = P^T @ A  (fockp)
    for (int u = 0; u < 16; ++u) {
        int idx = tid + 256 * u; int i = idx >> 6, j = idx & 63;
        float a = 0.f;
        for (int k = 0; k < BD; ++k) a += P[k * PITCH + i] * A[k * PITCH + j];
        V[i * PITCH + j] = a;
    }
    __syncthreads();

    // A = sym(fockp) = 0.5*(V + V^T)  (jnp.linalg.eigh symmetrize semantics)
    float s2 = 0.f;
    for (int u = 0; u < 16; ++u) {
        int idx = tid + 256 * u; int i = idx >> 6, j = idx & 63;
        float av = 0.5f * (V[i * PITCH + j] + V[j * PITCH + i]);
        A[i * PITCH + j] = av;
        s2 += av * av;
    }
    red[tid] = s2;
    __syncthreads();
    for (int st = 128; st > 0; st >>= 1) { if (tid < st) red[tid] += red[tid + st]; __syncthreads(); }
    float tol = fmaxf(red[0] * 1e-9f, 1e-30f);
    __syncthreads();

    // V = I
    for (int u = 0; u < 16; ++u) {
        int idx = tid + 256 * u; int i = idx >> 6, j = idx & 63;
        V[i * PITCH + j] = (i == j) ? 1.f : 0.f;
    }
    __syncthreads();

    int g  = tid >> 3;                       // group 0..31 (8 threads each)
    int t  = ((g & 7) << 2) | (g >> 3);      // pi(g): bank-conflict-free slot
    int c0 = tid & 7;

    // parallel cyclic Jacobi: 63 rounds of 32 disjoint pairs per sweep
    for (int sweep = 0; sweep < MAXSWEEP; ++sweep) {
        for (int r = 0; r < 63; ++r) {
            int p, q;
            if (t == 0) { p = 63; q = r; }
            else {
                int rp = r + t;      p = (rp >= 63) ? rp - 63 : rp;
                int rq = r + 63 - t; q = (rq >= 63) ? rq - 63 : rq;
            }
            // rotation params, computed redundantly by all 8 threads of group
            float app = A[p * PITCH + p], aqq = A[q * PITCH + q], apq = A[p * PITCH + q];
            float c = 1.f, s = 0.f;
            if (fabsf(apq) > 1e-36f) {
                float theta = (aqq - app) / (2.f * apq);
                float tt = 1.f / (fabsf(theta) + sqrtf(theta * theta + 1.f));
                if (theta < 0.f) tt = -tt;
                c = 1.f / sqrtf(tt * tt + 1.f);
                s = tt * c;
            }
            __builtin_amdgcn_wave_barrier();  // keep param reads before row writes
            // row update: B = J^T A   (rows p,q owned exclusively by this group)
#pragma unroll
            for (int j = 0; j < 8; ++j) {
                int col = c0 + 8 * j;
                float a = A[p * PITCH + col], b = A[q * PITCH + col];
                A[p * PITCH + col] = c * a - s * b;
                A[q * PITCH + col] = s * a + c * b;
            }
            __syncthreads();
            // col update: A = B J, V = V J  (cols p,q exclusive to this group)
#pragma unroll
            for (int j = 0; j < 8; ++j) {
                int row = c0 + 8 * j;
                float a = A[row * PITCH + p], b = A[row * PITCH + q];
                A[row * PITCH + p] = c * a - s * b;
                A[row * PITCH + q] = s * a + c * b;
                float va = V[row * PITCH + p], vb = V[row * PITCH + q];
                V[row * PITCH + p] = c * va - s * vb;
                V[row * PITCH + q] = s * va + c * vb;
            }
            __syncthreads();
        }
        // convergence: off-diagonal Frobenius^2
        float o2 = 0.f;
        for (int u = 0; u < 16; ++u) {
            int idx = tid + 256 * u; int i = idx >> 6, j = idx & 63;
            if (i != j) { float v = A[i * PITCH + j]; o2 += v * v; }
        }
        red[tid] = o2;
        __syncthreads();
        for (int st = 128; st > 0; st >>= 1) { if (tid < st) red[tid] += red[tid + st]; __syncthreads(); }
        if (red[0] <= tol) break;
        __syncthreads();
    }
    __syncthreads();

    // eigenvalues, ascending rank (stable), write Eorb
    if (tid < BD) evals[tid] = A[tid * PITCH + tid];
    __syncthreads();
    if (tid < BD) {
        float lam = evals[tid];
        int rnk = 0;
        for (int j2 = 0; j2 < BD; ++j2) {
            float o = evals[j2];
            rnk += (o < lam) || (o == lam && j2 < tid);
        }
        perm[rnk] = tid;
        Eorb[(size_t)m * BD + rnk] = lam;
    }
    __syncthreads();

    // orb_occ = phiS @ V[:, perm[0..31]]  -> into A[:, 0..31]
    for (int u = 0; u < 8; ++u) {
        int idx = tid + 256 * u; int i = idx >> 5, j = idx & 31;
        int pj = perm[j];
        float a = 0.f;
        for (int k = 0; k < BD; ++k) a += P[i * PITCH + k] * V[k * PITCH + pj];
        A[i * PITCH + j] = a;
    }
    __syncthreads();

    // rho = 2 * orb_occ @ orb_occ^T ; ener1 = sum(rho * H)
    float accE = 0.f;
    for (int u = 0; u < 16; ++u) {
        int idx = tid + 256 * u; int i = idx >> 6, j = idx & 63;
        float rv = 0.f;
        for (int tt = 0; tt < 32; ++tt) rv += A[i * PITCH + tt] * A[j * PITCH + tt];
        rv *= 2.f;
        rho_out[base + idx] = rv;
        accE += rv * Hws[base + idx];
    }
    red[tid] = accE;
    __syncthreads();
    for (int st = 128; st > 0; st >>= 1) { if (tid < st) red[tid] += red[tid + st]; __syncthreads(); }
    if (tid == 0) Eelec[m] = Eelec[m] + red[0];
}

// ---------------- launcher ----------------
extern "C" void kernel_launch(void* const* d_in, const int* in_sizes, int n_in,
                              void* d_out, int out_size, void* d_ws, size_t ws_size,
                              hipStream_t stream) {
    const float* x           = (const float*)d_in[0];
    const float* net_base    = (const float*)d_in[1];
    const float* rot_tensors = (const float*)d_in[2];
    const float* S           = (const float*)d_in[3];
    const float* G           = (const float*)d_in[4];
    const float* rho_in      = (const float*)d_in[5];
    const float* phiS        = (const float*)d_in[6];
    const float* qn          = (const float*)d_in[7];
    // d_in[8] occ_mask: constant (col < 32), folded into k_eig
    const int* scatter_idx   = (const int*)d_in[9];
    const int* rot_gather    = (const int*)d_in[10];
    const int* oper_gather   = (const int*)d_in[11];
    const int* rep_gather    = (const int*)d_in[12];
    const int* rep_seg       = (const int*)d_in[13];

    float* out   = (float*)d_out;
    float* oEelec = out;                               // NMOL
    float* oErep  = oEelec + NMOL;                     // NMOL
    float* oEorb  = oErep + NMOL;                      // NMOL*64
    float* oRho   = oEorb + (size_t)NMOL * BD;         // NMOL*64*64
    float* oF     = oRho + (size_t)NMOL * BD * BD;     // NMOL*64*64

    // workspace layout (~61.6 MB):
    float* ws_net = (float*)d_ws;                      // NN floats
    float* ws_rot = ws_net + NN;                       // ROT_LEN floats (+pad)
    float* ws_H   = ws_rot + 3000004;                  // NMOL*64*64 floats
    int*   winner = (int*)ws_H;                        // alias (dead before H is written)

    int nx = in_sizes[0];
    int total_ops = NMOL * BD * BD;

    k_copy<<<2048, 256, 0, stream>>>((const float4*)net_base, (float4*)ws_net, NN / 4);
    int gb = (nx + 255) / 256;
    k_scat_init <<<gb, 256, 0, stream>>>(scatter_idx, winner, nx);
    k_scat_max  <<<gb, 256, 0, stream>>>(scatter_idx, winner, nx);
    k_scat_write<<<gb, 256, 0, stream>>>(scatter_idx, winner, x, ws_net, nx);
    k_rot<<<(NROT_C + 255) / 256, 256, 0, stream>>>(ws_net, rot_gather, rot_tensors, ws_rot, NROT_C);
    k_oper<<<(total_ops + 255) / 256, 256, 0, stream>>>(ws_rot, oper_gather, ws_H, total_ops);
    k_fock<<<NMOL, 256, 0, stream>>>(S, G, rho_in, qn, ws_H, oF, oEelec);
    k_erep<<<NMOL, 64, 0, stream>>>(ws_net, rep_gather, rep_seg, oErep, NREP_C);
    k_eig<<<NMOL, 256, 0, stream>>>(oF, phiS, ws_H, oEorb, oRho, oEelec);
}

// Round 3
// 1244.335 us; speedup vs baseline: 4.8469x; 2.8385x over previous
//
#include <hip/hip_runtime.h>

// ---------------- problem constants (match reference) ----------------
#define NMOL   2048
#define BD     64
#define PITCH  65            // LDS row pitch: bank = (row + col) % 32
#define NROT_C 1000000
#define NN     4000000       // len(net_vals)
#define NREP_C 500000
#define VSPLIT 1953          // Vocc for mat<VSPLIT lives in ws_net, rest in ws_rot

// ---------------- stage 1: net_vals = net_base; scatter x (last write wins) --
__global__ __launch_bounds__(256) void k_copy(const float4* __restrict__ src,
                                              float4* __restrict__ dst, int n4) {
    int i = blockIdx.x * blockDim.x + threadIdx.x;
    int stride = gridDim.x * blockDim.x;
    for (; i < n4; i += stride) dst[i] = src[i];
}

__global__ __launch_bounds__(256) void k_scat_init(const int* __restrict__ idx,
                                                   int* __restrict__ winner, int nx) {
    int i = blockIdx.x * blockDim.x + threadIdx.x;
    if (i < nx) winner[idx[i]] = -1;
}
__global__ __launch_bounds__(256) void k_scat_max(const int* __restrict__ idx,
                                                  int* __restrict__ winner, int nx) {
    int i = blockIdx.x * blockDim.x + threadIdx.x;
    if (i < nx) atomicMax(&winner[idx[i]], i);
}
__global__ __launch_bounds__(256) void k_scat_write(const int* __restrict__ idx,
                                                    const int* __restrict__ winner,
                                                    const float* __restrict__ x,
                                                    float* __restrict__ net, int nx) {
    int i = blockIdx.x * blockDim.x + threadIdx.x;
    if (i < nx && winner[idx[i]] == i) net[idx[i]] = x[i];
}

// ---------------- stage 2: rotations + oper gather ----------------
__global__ __launch_bounds__(256) void k_rot(const float* __restrict__ net,
                                             const int* __restrict__ rg,
                                             const float* __restrict__ rt,
                                             float* __restrict__ rot_out, int nrot) {
    int r = blockIdx.x * blockDim.x + threadIdx.x;
    if (r == 0) { rot_out[0] = 0.f; rot_out[1] = 1.f; }
    if (r >= nrot) return;
    int i0 = rg[3 * r], i1 = rg[3 * r + 1], i2 = rg[3 * r + 2];
    float v0 = net[i0], v1 = net[i1], v2 = net[i2];
    const float* T = rt + (size_t)r * 9;
    rot_out[2 + 3 * r + 0] = T[0] * v0 + T[1] * v1 + T[2] * v2;
    rot_out[2 + 3 * r + 1] = T[3] * v0 + T[4] * v1 + T[5] * v2;
    rot_out[2 + 3 * r + 2] = T[6] * v0 + T[7] * v1 + T[8] * v2;
}

__global__ __launch_bounds__(256) void k_oper(const float* __restrict__ rot_out,
                                              const int* __restrict__ og,
                                              float* __restrict__ H, int total) {
    int i = blockIdx.x * blockDim.x + threadIdx.x;
    if (i < total) H[i] = rot_out[og[i]];
}

// ---------------- stage 3: Fock assembly, one block per molecule ------------
__global__ __launch_bounds__(256) void k_fock(const float* __restrict__ S,
                                              const float* __restrict__ G,
                                              const float* __restrict__ rho,
                                              const float* __restrict__ qn,
                                              const float* __restrict__ H,
                                              float* __restrict__ F,
                                              float* __restrict__ Eelec) {
    __shared__ float Ssh[BD * PITCH];
    __shared__ float part[BD * 4];
    __shared__ float dQ[BD], ep[BD];
    int m = blockIdx.x, tid = threadIdx.x;
    size_t base = (size_t)m * BD * BD;
    int i = tid >> 2, jq = tid & 3;
    int j0 = jq * 16;

    float acc = 0.f;
#pragma unroll
    for (int jj = 0; jj < 16; ++jj) {
        int j = j0 + jj;
        float sv = S[base + i * BD + j];
        float rv = rho[base + i * BD + j];
        Ssh[i * PITCH + j] = sv;
        acc += sv * rv;
    }
    part[i * 4 + jq] = acc;
    __syncthreads();
    if (tid < BD)
        dQ[tid] = qn[(size_t)m * BD + tid] -
                  (part[tid * 4] + part[tid * 4 + 1] + part[tid * 4 + 2] + part[tid * 4 + 3]);
    __syncthreads();

    float acc2 = 0.f;
#pragma unroll
    for (int jj = 0; jj < 16; ++jj) {
        int j = j0 + jj;
        acc2 += G[base + i * BD + j] * dQ[j];
    }
    part[i * 4 + jq] = acc2;
    __syncthreads();
    if (tid < BD) {
        float e = part[tid * 4] + part[tid * 4 + 1] + part[tid * 4 + 2] + part[tid * 4 + 3];
        ep[tid] = e;
        float v = dQ[tid] * e;
        for (int off = 32; off > 0; off >>= 1) v += __shfl_down(v, off, 64);
        if (tid == 0) Eelec[m] = 0.5f * v;      // ener2; k_post adds ener1 later
    }
    __syncthreads();

#pragma unroll
    for (int u = 0; u < 16; ++u) {
        int idx = tid + 256 * u;
        int i2 = idx >> 6, j2 = idx & 63;
        F[base + idx] = H[base + idx] - 0.5f * Ssh[i2 * PITCH + j2] * (ep[i2] + ep[j2]);
    }
}

// ---------------- stage 4: Erep segment sum (deterministic, no atomics) -----
__global__ __launch_bounds__(64) void k_erep(const float* __restrict__ net,
                                             const int* __restrict__ rg,
                                             const int* __restrict__ seg,
                                             float* __restrict__ Erep, int nrep) {
    int m = blockIdx.x, lane = threadIdx.x;
    int lo = 0, hi = nrep;
    while (lo < hi) { int mid = (lo + hi) >> 1; if (seg[mid] < m) lo = mid + 1; else hi = mid; }
    int start = lo;
    hi = nrep;
    while (lo < hi) { int mid = (lo + hi) >> 1; if (seg[mid] < m + 1) lo = mid + 1; else hi = mid; }
    int end = lo;
    float s = 0.f;
    for (int k = start + lane; k < end; k += 64) s += net[rg[k]];
    for (int off = 32; off > 0; off >>= 1) s += __shfl_down(s, off, 64);
    if (lane == 0) Erep[m] = s;
}

// ---------------- stage 5: fockp + one-sided register Jacobi ----------------
// Block = 256 threads = 4 waves; each wave solves one matrix. Prologue builds
// B = sym(P^T F P) + mu*I for the block's 4 matrices via LDS matmuls; then each
// wave runs one-sided Hestenes Jacobi with columns in registers (lane l holds
// column l of W), XOR-tournament pairing (round m: partner = lane^m), shfl_xor
// exchange. No LDS, no barriers, no bank conflicts in the sweep loop.
#define MAXSWEEP 12
__global__ __launch_bounds__(256) void k_eigj(const float* __restrict__ F,
                                              const float* __restrict__ phiS,
                                              float* __restrict__ Eorb,
                                              float* __restrict__ ws_net,
                                              float* __restrict__ ws_rot) {
    __shared__ float Pl[BD * PITCH];
    __shared__ float Xl[BD * PITCH];
    __shared__ float Bl[BD * PITCH];
    __shared__ float s_mu;

    int tid = threadIdx.x;
    int wave = tid >> 6, lane = tid & 63;
    // 4x4 output tile coords for matmuls
    int ti = tid >> 4, tj = tid & 15;      // 16x16 thread grid
    int i0 = ti * 4, j0 = tj * 4;

    float w[64];
    float mu_reg = 0.f;

    for (int mm = 0; mm < 4; ++mm) {
        int mat = blockIdx.x * 4 + mm;
        size_t base = (size_t)mat * BD * BD;
        // load P <- phiS, Bl <- F
#pragma unroll
        for (int u = 0; u < 16; ++u) {
            int idx = tid + 256 * u; int i = idx >> 6, j = idx & 63;
            Pl[i * PITCH + j] = phiS[base + idx];
            Bl[i * PITCH + j] = F[base + idx];
        }
        __syncthreads();
        // Xl = F @ P   (Bl holds F)
        {
            float a00=0,a01=0,a02=0,a03=0, a10=0,a11=0,a12=0,a13=0;
            float a20=0,a21=0,a22=0,a23=0, a30=0,a31=0,a32=0,a33=0;
            for (int k = 0; k < BD; ++k) {
                float f0 = Bl[(i0+0)*PITCH+k], f1 = Bl[(i0+1)*PITCH+k];
                float f2 = Bl[(i0+2)*PITCH+k], f3 = Bl[(i0+3)*PITCH+k];
                float p0 = Pl[k*PITCH+j0+0], p1 = Pl[k*PITCH+j0+1];
                float p2 = Pl[k*PITCH+j0+2], p3 = Pl[k*PITCH+j0+3];
                a00 += f0*p0; a01 += f0*p1; a02 += f0*p2; a03 += f0*p3;
                a10 += f1*p0; a11 += f1*p1; a12 += f1*p2; a13 += f1*p3;
                a20 += f2*p0; a21 += f2*p1; a22 += f2*p2; a23 += f2*p3;
                a30 += f3*p0; a31 += f3*p1; a32 += f3*p2; a33 += f3*p3;
            }
            __syncthreads();
            Xl[(i0+0)*PITCH+j0+0]=a00; Xl[(i0+0)*PITCH+j0+1]=a01; Xl[(i0+0)*PITCH+j0+2]=a02; Xl[(i0+0)*PITCH+j0+3]=a03;
            Xl[(i0+1)*PITCH+j0+0]=a10; Xl[(i0+1)*PITCH+j0+1]=a11; Xl[(i0+1)*PITCH+j0+2]=a12; Xl[(i0+1)*PITCH+j0+3]=a13;
            Xl[(i0+2)*PITCH+j0+0]=a20; Xl[(i0+2)*PITCH+j0+1]=a21; Xl[(i0+2)*PITCH+j0+2]=a22; Xl[(i0+2)*PITCH+j0+3]=a23;
            Xl[(i0+3)*PITCH+j0+0]=a30; Xl[(i0+3)*PITCH+j0+1]=a31; Xl[(i0+3)*PITCH+j0+2]=a32; Xl[(i0+3)*PITCH+j0+3]=a33;
        }
        __syncthreads();
        // Bl = P^T @ Xl (fockp) — overwrites F (fully consumed)
        {
            float a00=0,a01=0,a02=0,a03=0, a10=0,a11=0,a12=0,a13=0;
            float a20=0,a21=0,a22=0,a23=0, a30=0,a31=0,a32=0,a33=0;
            for (int k = 0; k < BD; ++k) {
                float f0 = Pl[k*PITCH+i0+0], f1 = Pl[k*PITCH+i0+1];
                float f2 = Pl[k*PITCH+i0+2], f3 = Pl[k*PITCH+i0+3];
                float p0 = Xl[k*PITCH+j0+0], p1 = Xl[k*PITCH+j0+1];
                float p2 = Xl[k*PITCH+j0+2], p3 = Xl[k*PITCH+j0+3];
                a00 += f0*p0; a01 += f0*p1; a02 += f0*p2; a03 += f0*p3;
                a10 += f1*p0; a11 += f1*p1; a12 += f1*p2; a13 += f1*p3;
                a20 += f2*p0; a21 += f2*p1; a22 += f2*p2; a23 += f2*p3;
                a30 += f3*p0; a31 += f3*p1; a32 += f3*p2; a33 += f3*p3;
            }
            __syncthreads();
            Bl[(i0+0)*PITCH+j0+0]=a00; Bl[(i0+0)*PITCH+j0+1]=a01; Bl[(i0+0)*PITCH+j0+2]=a02; Bl[(i0+0)*PITCH+j0+3]=a03;
            Bl[(i0+1)*PITCH+j0+0]=a10; Bl[(i0+1)*PITCH+j0+1]=a11; Bl[(i0+1)*PITCH+j0+2]=a12; Bl[(i0+1)*PITCH+j0+3]=a13;
            Bl[(i0+2)*PITCH+j0+0]=a20; Bl[(i0+2)*PITCH+j0+1]=a21; Bl[(i0+2)*PITCH+j0+2]=a22; Bl[(i0+2)*PITCH+j0+3]=a23;
            Bl[(i0+3)*PITCH+j0+0]=a30; Bl[(i0+3)*PITCH+j0+1]=a31; Bl[(i0+3)*PITCH+j0+2]=a32; Bl[(i0+3)*PITCH+j0+3]=a33;
        }
        __syncthreads();
        // Xl = sym(Bl)
#pragma unroll
        for (int u = 0; u < 16; ++u) {
            int idx = tid + 256 * u; int i = idx >> 6, j = idx & 63;
            Xl[i * PITCH + j] = 0.5f * (Bl[i * PITCH + j] + Bl[j * PITCH + i]);
        }
        __syncthreads();
        // Gershgorin bound -> mu
        if (tid < BD) {
            float rs = 0.f;
            for (int j = 0; j < BD; ++j) rs += fabsf(Xl[tid * PITCH + j]);
            for (int off = 32; off > 0; off >>= 1) rs = fmaxf(rs, __shfl_down(rs, off, 64));
            if (tid == 0) s_mu = 1.05f * rs + 0.5f;
        }
        __syncthreads();
        // wave mm grabs its columns: w = B[:, lane] = Xl[:, lane] + mu*e_lane
        if (wave == mm) {
            float mu = s_mu;
#pragma unroll
            for (int k = 0; k < BD; ++k)
                w[k] = Xl[k * PITCH + lane] + ((k == lane) ? mu : 0.f);
            mu_reg = mu;
        }
        __syncthreads();
    }

    // ---- one-sided Jacobi sweeps (register-resident, per-wave) ----
    float nrm = 0.f;
#pragma unroll
    for (int k = 0; k < BD; ++k) nrm += w[k] * w[k];

    int conv = 0;
    for (int sweep = 0; sweep < MAXSWEEP && !conv; ++sweep) {
        // refresh norm (kill incremental drift)
        float nr = 0.f;
#pragma unroll
        for (int k = 0; k < BD; ++k) nr += w[k] * w[k];
        nrm = nr;
        float biggest = 0.f;
        for (int m = 1; m < 64; ++m) {
            float pa = __shfl_xor(nrm, m, 64);
            float pw[64];
            float g = 0.f;
#pragma unroll
            for (int k = 0; k < BD; ++k) {
                pw[k] = __shfl_xor(w[k], m, 64);
                g = fmaf(w[k], pw[k], g);
            }
            bool isP = lane < (lane ^ m);
            float a = isP ? nrm : pa;
            float b = isP ? pa : nrm;
            biggest = fmaxf(biggest, g * g / (a * b));
            float c = 1.f, s = 0.f;
            if (fabsf(g) > 1e-37f) {
                float tau = (b - a) / (2.f * g);
                float tt = 1.f / (fabsf(tau) + sqrtf(tau * tau + 1.f));
                if (tau < 0.f) tt = -tt;
                c = 1.f / sqrtf(tt * tt + 1.f);
                s = tt * c;
                float cc = c * c, ss = s * s, cs2 = 2.f * c * s * g;
                nrm = isP ? (cc * a - cs2 + ss * b) : (ss * a + cs2 + cc * b);
            }
            float sp = isP ? -s : s;
#pragma unroll
            for (int k = 0; k < BD; ++k)
                w[k] = c * w[k] + sp * pw[k];
        }
#pragma unroll
        for (int off = 32; off > 0; off >>= 1)
            biggest = fmaxf(biggest, __shfl_xor(biggest, off, 64));
        conv = (biggest < 1e-12f);
    }

    // ---- extraction: lambda = ||w|| - mu, v = w/||w|| ----
    float l2 = 0.f;
#pragma unroll
    for (int k = 0; k < BD; ++k) l2 += w[k] * w[k];
    float lamB = sqrtf(l2);
    float lamA = lamB - mu_reg;

    int rnk = 0;
    for (int j = 0; j < BD; ++j) {
        float lj = __shfl(lamA, j, 64);
        rnk += (lj < lamA) || (lj == lamA && j < lane);
    }
    int mat = blockIdx.x * 4 + wave;
    Eorb[(size_t)mat * BD + rnk] = lamA;

    if (rnk < 32) {
        float inv = 1.f / lamB;
        float* vbase = (mat < VSPLIT) ? (ws_net + (size_t)mat * 2048)
                                      : (ws_rot + (size_t)(mat - VSPLIT) * 2048);
#pragma unroll
        for (int k = 0; k < BD; ++k)
            vbase[k * 32 + rnk] = w[k] * inv;
    }
}

// ---------------- stage 6: orb = P@Vocc, rho = 2*orb@orb^T, ener1 -----------
__global__ __launch_bounds__(256) void k_post(const float* __restrict__ phiS,
                                              const float* __restrict__ ws_net,
                                              const float* __restrict__ ws_rot,
                                              const float* __restrict__ Hws,
                                              float* __restrict__ rho_out,
                                              float* __restrict__ Eelec) {
    __shared__ float Pl[BD * PITCH];
    __shared__ float Vo[BD * 33];
    __shared__ float Orb[BD * 33];
    __shared__ float red[256];

    int mat = blockIdx.x, tid = threadIdx.x;
    size_t base = (size_t)mat * BD * BD;
    const float* vbase = (mat < VSPLIT) ? (ws_net + (size_t)mat * 2048)
                                        : (ws_rot + (size_t)(mat - VSPLIT) * 2048);
#pragma unroll
    for (int u = 0; u < 16; ++u) {
        int idx = tid + 256 * u; int i = idx >> 6, j = idx & 63;
        Pl[i * PITCH + j] = phiS[base + idx];
    }
#pragma unroll
    for (int u = 0; u < 8; ++u) {
        int idx = tid * 8 + u;            // 0..2047
        int k = idx >> 5, r = idx & 31;
        Vo[k * 33 + r] = vbase[idx];
    }
    __syncthreads();

    // Orb[i][r] = sum_k Pl[i][k] * Vo[k][r]; thread -> (i = tid>>2, r0 = (tid&3)*8)
    {
        int i = tid >> 2, r0 = (tid & 3) * 8;
        float acc0=0,acc1=0,acc2=0,acc3=0,acc4=0,acc5=0,acc6=0,acc7=0;
        for (int k = 0; k < BD; ++k) {
            float pv = Pl[i * PITCH + k];
            acc0 += pv * Vo[k*33 + r0+0]; acc1 += pv * Vo[k*33 + r0+1];
            acc2 += pv * Vo[k*33 + r0+2]; acc3 += pv * Vo[k*33 + r0+3];
            acc4 += pv * Vo[k*33 + r0+4]; acc5 += pv * Vo[k*33 + r0+5];
            acc6 += pv * Vo[k*33 + r0+6]; acc7 += pv * Vo[k*33 + r0+7];
        }
        Orb[i*33 + r0+0]=acc0; Orb[i*33 + r0+1]=acc1; Orb[i*33 + r0+2]=acc2; Orb[i*33 + r0+3]=acc3;
        Orb[i*33 + r0+4]=acc4; Orb[i*33 + r0+5]=acc5; Orb[i*33 + r0+6]=acc6; Orb[i*33 + r0+7]=acc7;
    }
    __syncthreads();

    // rho = 2*Orb@Orb^T (K=32), 4x4 tile per thread; ener1 = sum(rho*H)
    float accE = 0.f;
    {
        int ti = tid >> 4, tj = tid & 15;
        int i0 = ti * 4, j0 = tj * 4;
        float a[4][4];
#pragma unroll
        for (int u = 0; u < 4; ++u)
#pragma unroll
            for (int v = 0; v < 4; ++v) a[u][v] = 0.f;
        for (int r = 0; r < 32; ++r) {
            float o0 = Orb[(i0+0)*33 + r], o1 = Orb[(i0+1)*33 + r];
            float o2 = Orb[(i0+2)*33 + r], o3 = Orb[(i0+3)*33 + r];
            float q0 = Orb[(j0+0)*33 + r], q1 = Orb[(j0+1)*33 + r];
            float q2 = Orb[(j0+2)*33 + r], q3 = Orb[(j0+3)*33 + r];
            a[0][0]+=o0*q0; a[0][1]+=o0*q1; a[0][2]+=o0*q2; a[0][3]+=o0*q3;
            a[1][0]+=o1*q0; a[1][1]+=o1*q1; a[1][2]+=o1*q2; a[1][3]+=o1*q3;
            a[2][0]+=o2*q0; a[2][1]+=o2*q1; a[2][2]+=o2*q2; a[2][3]+=o2*q3;
            a[3][0]+=o3*q0; a[3][1]+=o3*q1; a[3][2]+=o3*q2; a[3][3]+=o3*q3;
        }
#pragma unroll
        for (int u = 0; u < 4; ++u) {
            float4 rv;
            rv.x = 2.f*a[u][0]; rv.y = 2.f*a[u][1]; rv.z = 2.f*a[u][2]; rv.w = 2.f*a[u][3];
            size_t off = base + (size_t)(i0+u) * BD + j0;
            *reinterpret_cast<float4*>(&rho_out[off]) = rv;
            const float4 hv = *reinterpret_cast<const float4*>(&Hws[off]);
            accE += rv.x*hv.x + rv.y*hv.y + rv.z*hv.z + rv.w*hv.w;
        }
    }
    red[tid] = accE;
    __syncthreads();
    for (int st = 128; st > 0; st >>= 1) { if (tid < st) red[tid] += red[tid + st]; __syncthreads(); }
    if (tid == 0) Eelec[mat] = Eelec[mat] + red[0];
}

// ---------------- launcher ----------------
extern "C" void kernel_launch(void* const* d_in, const int* in_sizes, int n_in,
                              void* d_out, int out_size, void* d_ws, size_t ws_size,
                              hipStream_t stream) {
    const float* x           = (const float*)d_in[0];
    const float* net_base    = (const float*)d_in[1];
    const float* rot_tensors = (const float*)d_in[2];
    const float* S           = (const float*)d_in[3];
    const float* G           = (const float*)d_in[4];
    const float* rho_in      = (const float*)d_in[5];
    const float* phiS        = (const float*)d_in[6];
    const float* qn          = (const float*)d_in[7];
    // d_in[8] occ_mask: constant (col < 32), folded into k_eigj/k_post
    const int* scatter_idx   = (const int*)d_in[9];
    const int* rot_gather    = (const int*)d_in[10];
    const int* oper_gather   = (const int*)d_in[11];
    const int* rep_gather    = (const int*)d_in[12];
    const int* rep_seg       = (const int*)d_in[13];

    float* out   = (float*)d_out;
    float* oEelec = out;                               // NMOL
    float* oErep  = oEelec + NMOL;                     // NMOL
    float* oEorb  = oErep + NMOL;                      // NMOL*64
    float* oRho   = oEorb + (size_t)NMOL * BD;         // NMOL*64*64
    float* oF     = oRho + (size_t)NMOL * BD * BD;     // NMOL*64*64

    // workspace layout (~61.6 MB):
    float* ws_net = (float*)d_ws;                      // NN floats (Vocc reuse after k_erep)
    float* ws_rot = ws_net + NN;                       // 3,000,004 floats (Vocc spill reuse)
    float* ws_H   = ws_rot + 3000004;                  // NMOL*64*64 floats
    int*   winner = (int*)ws_H;                        // alias (dead before H is written)

    int nx = in_sizes[0];
    int total_ops = NMOL * BD * BD;

    k_copy<<<2048, 256, 0, stream>>>((const float4*)net_base, (float4*)ws_net, NN / 4);
    int gb = (nx + 255) / 256;
    k_scat_init <<<gb, 256, 0, stream>>>(scatter_idx, winner, nx);
    k_scat_max  <<<gb, 256, 0, stream>>>(scatter_idx, winner, nx);
    k_scat_write<<<gb, 256, 0, stream>>>(scatter_idx, winner, x, ws_net, nx);
    k_rot<<<(NROT_C + 255) / 256, 256, 0, stream>>>(ws_net, rot_gather, rot_tensors, ws_rot, NROT_C);
    k_oper<<<(total_ops + 255) / 256, 256, 0, stream>>>(ws_rot, oper_gather, ws_H, total_ops);
    k_fock<<<NMOL, 256, 0, stream>>>(S, G, rho_in, qn, ws_H, oF, oEelec);
    // Erep BEFORE k_eigj (k_eigj overwrites ws_net/ws_rot with Vocc)
    k_erep<<<NMOL, 64, 0, stream>>>(ws_net, rep_gather, rep_seg, oErep, NREP_C);
    k_eigj<<<NMOL / 4, 256, 0, stream>>>(oF, phiS, oEorb, ws_net, ws_rot);
    k_post<<<NMOL, 256, 0, stream>>>(phiS, ws_net, ws_rot, ws_H, oRho, oEelec);
}

// Round 4
// 1048.097 us; speedup vs baseline: 5.7544x; 1.1872x over previous
//
#include <hip/hip_runtime.h>

// ---------------- problem constants (match reference) ----------------
#define NMOL   2048
#define BD     64
#define PITCH  65            // LDS row pitch for k_fock/k_post
#define PP2    68            // k_prep pitch: 16B-aligned rows, odd-ish bank stride
#define NROT_C 1000000
#define NN     4000000       // len(net_vals)
#define NREP_C 500000
#define VSPLIT 1953          // Vocc for mat<VSPLIT lives in ws_net, rest in ws_rot

// ---------------- stage 1: net_vals = net_base; scatter x (last write wins) --
__global__ __launch_bounds__(256) void k_copy(const float4* __restrict__ src,
                                              float4* __restrict__ dst, int n4) {
    int i = blockIdx.x * blockDim.x + threadIdx.x;
    int stride = gridDim.x * blockDim.x;
    for (; i < n4; i += stride) dst[i] = src[i];
}

__global__ __launch_bounds__(256) void k_scat_init(const int* __restrict__ idx,
                                                   int* __restrict__ winner, int nx) {
    int i = blockIdx.x * blockDim.x + threadIdx.x;
    if (i < nx) winner[idx[i]] = -1;
}
__global__ __launch_bounds__(256) void k_scat_max(const int* __restrict__ idx,
                                                  int* __restrict__ winner, int nx) {
    int i = blockIdx.x * blockDim.x + threadIdx.x;
    if (i < nx) atomicMax(&winner[idx[i]], i);
}
__global__ __launch_bounds__(256) void k_scat_write(const int* __restrict__ idx,
                                                    const int* __restrict__ winner,
                                                    const float* __restrict__ x,
                                                    float* __restrict__ net, int nx) {
    int i = blockIdx.x * blockDim.x + threadIdx.x;
    if (i < nx && winner[idx[i]] == i) net[idx[i]] = x[i];
}

// ---------------- stage 2: rotations + oper gather ----------------
__global__ __launch_bounds__(256) void k_rot(const float* __restrict__ net,
                                             const int* __restrict__ rg,
                                             const float* __restrict__ rt,
                                             float* __restrict__ rot_out, int nrot) {
    int r = blockIdx.x * blockDim.x + threadIdx.x;
    if (r == 0) { rot_out[0] = 0.f; rot_out[1] = 1.f; }
    if (r >= nrot) return;
    int i0 = rg[3 * r], i1 = rg[3 * r + 1], i2 = rg[3 * r + 2];
    float v0 = net[i0], v1 = net[i1], v2 = net[i2];
    const float* T = rt + (size_t)r * 9;
    rot_out[2 + 3 * r + 0] = T[0] * v0 + T[1] * v1 + T[2] * v2;
    rot_out[2 + 3 * r + 1] = T[3] * v0 + T[4] * v1 + T[5] * v2;
    rot_out[2 + 3 * r + 2] = T[6] * v0 + T[7] * v1 + T[8] * v2;
}

__global__ __launch_bounds__(256) void k_oper(const float* __restrict__ rot_out,
                                              const int* __restrict__ og,
                                              float* __restrict__ H, int total) {
    int i = blockIdx.x * blockDim.x + threadIdx.x;
    if (i < total) H[i] = rot_out[og[i]];
}

// ---------------- stage 3: Fock assembly, one block per molecule ------------
__global__ __launch_bounds__(256) void k_fock(const float* __restrict__ S,
                                              const float* __restrict__ G,
                                              const float* __restrict__ rho,
                                              const float* __restrict__ qn,
                                              const float* __restrict__ H,
                                              float* __restrict__ F,
                                              float* __restrict__ Eelec) {
    __shared__ float Ssh[BD * PITCH];
    __shared__ float part[BD * 4];
    __shared__ float dQ[BD], ep[BD];
    int m = blockIdx.x, tid = threadIdx.x;
    size_t base = (size_t)m * BD * BD;
    int i = tid >> 2, jq = tid & 3;
    int j0 = jq * 16;

    float acc = 0.f;
#pragma unroll
    for (int jj = 0; jj < 16; ++jj) {
        int j = j0 + jj;
        float sv = S[base + i * BD + j];
        float rv = rho[base + i * BD + j];
        Ssh[i * PITCH + j] = sv;
        acc += sv * rv;
    }
    part[i * 4 + jq] = acc;
    __syncthreads();
    if (tid < BD)
        dQ[tid] = qn[(size_t)m * BD + tid] -
                  (part[tid * 4] + part[tid * 4 + 1] + part[tid * 4 + 2] + part[tid * 4 + 3]);
    __syncthreads();

    float acc2 = 0.f;
#pragma unroll
    for (int jj = 0; jj < 16; ++jj) {
        int j = j0 + jj;
        acc2 += G[base + i * BD + j] * dQ[j];
    }
    part[i * 4 + jq] = acc2;
    __syncthreads();
    if (tid < BD) {
        float e = part[tid * 4] + part[tid * 4 + 1] + part[tid * 4 + 2] + part[tid * 4 + 3];
        ep[tid] = e;
        float v = dQ[tid] * e;
        for (int off = 32; off > 0; off >>= 1) v += __shfl_down(v, off, 64);
        if (tid == 0) Eelec[m] = 0.5f * v;      // ener2; k_post adds ener1 later
    }
    __syncthreads();

#pragma unroll
    for (int u = 0; u < 16; ++u) {
        int idx = tid + 256 * u;
        int i2 = idx >> 6, j2 = idx & 63;
        F[base + idx] = H[base + idx] - 0.5f * Ssh[i2 * PITCH + j2] * (ep[i2] + ep[j2]);
    }
}

// ---------------- stage 4: Erep segment sum (deterministic, no atomics) -----
__global__ __launch_bounds__(64) void k_erep(const float* __restrict__ net,
                                             const int* __restrict__ rg,
                                             const int* __restrict__ seg,
                                             float* __restrict__ Erep, int nrep) {
    int m = blockIdx.x, lane = threadIdx.x;
    int lo = 0, hi = nrep;
    while (lo < hi) { int mid = (lo + hi) >> 1; if (seg[mid] < m) lo = mid + 1; else hi = mid; }
    int start = lo;
    hi = nrep;
    while (lo < hi) { int mid = (lo + hi) >> 1; if (seg[mid] < m + 1) lo = mid + 1; else hi = mid; }
    int end = lo;
    float s = 0.f;
    for (int k = start + lane; k < end; k += 64) s += net[rg[k]];
    for (int off = 32; off > 0; off >>= 1) s += __shfl_down(s, off, 64);
    if (lane == 0) Erep[m] = s;
}

// ---------------- stage 5a: k_prep — B = sym(P^T F P) + mu*I ----------------
// One matrix per block. F stored transposed in LDS so both matmul operands
// read as float4 (2x ds_read_b128 per k-step). Writes B col-major to scratch.
__global__ __launch_bounds__(256) void k_prep(const float* __restrict__ F,
                                              const float* __restrict__ phiS,
                                              float* __restrict__ Bc,
                                              float* __restrict__ mu_out) {
    __shared__ float Ft[BD * PP2];   // F^T, later fockp
    __shared__ float PL[BD * PP2];   // phiS row-major
    __shared__ float XL[BD * PP2];   // F @ P
    __shared__ float rs[BD];
    __shared__ float s_mu;
    int mat = blockIdx.x, tid = threadIdx.x;
    size_t base = (size_t)mat * BD * BD;

#pragma unroll
    for (int u = 0; u < 16; ++u) {
        int idx = tid + 256 * u; int r = idx >> 6, c = idx & 63;
        Ft[c * PP2 + r] = F[base + idx];
        PL[r * PP2 + c] = phiS[base + idx];
    }
    __syncthreads();

    int ti = tid >> 4, tj = tid & 15;
    int i0 = ti * 4, j0 = tj * 4;

    // XL = F @ P
    {
        float a[4][4];
#pragma unroll
        for (int u = 0; u < 4; ++u)
#pragma unroll
            for (int v = 0; v < 4; ++v) a[u][v] = 0.f;
        for (int k = 0; k < BD; ++k) {
            float4 av = *reinterpret_cast<const float4*>(&Ft[k * PP2 + i0]);
            float4 bv = *reinterpret_cast<const float4*>(&PL[k * PP2 + j0]);
            a[0][0] += av.x*bv.x; a[0][1] += av.x*bv.y; a[0][2] += av.x*bv.z; a[0][3] += av.x*bv.w;
            a[1][0] += av.y*bv.x; a[1][1] += av.y*bv.y; a[1][2] += av.y*bv.z; a[1][3] += av.y*bv.w;
            a[2][0] += av.z*bv.x; a[2][1] += av.z*bv.y; a[2][2] += av.z*bv.z; a[2][3] += av.z*bv.w;
            a[3][0] += av.w*bv.x; a[3][1] += av.w*bv.y; a[3][2] += av.w*bv.z; a[3][3] += av.w*bv.w;
        }
#pragma unroll
        for (int u = 0; u < 4; ++u)
            *reinterpret_cast<float4*>(&XL[(i0 + u) * PP2 + j0]) =
                make_float4(a[u][0], a[u][1], a[u][2], a[u][3]);
    }
    __syncthreads();

    // Ft = P^T @ XL  (fockp; overwrites F^T)
    {
        float a[4][4];
#pragma unroll
        for (int u = 0; u < 4; ++u)
#pragma unroll
            for (int v = 0; v < 4; ++v) a[u][v] = 0.f;
        for (int k = 0; k < BD; ++k) {
            float4 av = *reinterpret_cast<const float4*>(&PL[k * PP2 + i0]);
            float4 bv = *reinterpret_cast<const float4*>(&XL[k * PP2 + j0]);
            a[0][0] += av.x*bv.x; a[0][1] += av.x*bv.y; a[0][2] += av.x*bv.z; a[0][3] += av.x*bv.w;
            a[1][0] += av.y*bv.x; a[1][1] += av.y*bv.y; a[1][2] += av.y*bv.z; a[1][3] += av.y*bv.w;
            a[2][0] += av.z*bv.x; a[2][1] += av.z*bv.y; a[2][2] += av.z*bv.z; a[2][3] += av.z*bv.w;
            a[3][0] += av.w*bv.x; a[3][1] += av.w*bv.y; a[3][2] += av.w*bv.z; a[3][3] += av.w*bv.w;
        }
        __syncthreads();
#pragma unroll
        for (int u = 0; u < 4; ++u)
            *reinterpret_cast<float4*>(&Ft[(i0 + u) * PP2 + j0]) =
                make_float4(a[u][0], a[u][1], a[u][2], a[u][3]);
    }
    __syncthreads();

    // Gershgorin row sums of sym(Ft)
    {
        int r = tid >> 2, part = tid & 3;
        float s = 0.f;
#pragma unroll
        for (int jj = 0; jj < 16; ++jj) {
            int j = part * 16 + jj;
            s += fabsf(0.5f * (Ft[r * PP2 + j] + Ft[j * PP2 + r]));
        }
        s += __shfl_xor(s, 1, 64);
        s += __shfl_xor(s, 2, 64);
        if (part == 0) rs[r] = s;
    }
    __syncthreads();
    if (tid < BD) {
        float v = rs[tid];
        for (int off = 32; off > 0; off >>= 1) v = fmaxf(v, __shfl_down(v, off, 64));
        if (tid == 0) { s_mu = 1.05f * v + 0.5f; mu_out[mat] = 1.05f * v + 0.5f; }
    }
    __syncthreads();

    // write B col-major (+mu on diag); symmetric so (c,r) orientation is free
    float mu = s_mu;
#pragma unroll
    for (int u = 0; u < 16; ++u) {
        int idx = tid + 256 * u; int c = idx >> 6, r = idx & 63;
        float v = 0.5f * (Ft[c * PP2 + r] + Ft[r * PP2 + c]);
        if (c == r) v += mu;
        Bc[base + idx] = v;
    }
}

// ---------------- stage 5b: k_eigs — register one-sided Jacobi --------------
__device__ __forceinline__ float2 f2fma(float2 a, float2 b, float2 c) {
    return make_float2(fmaf(a.x, b.x, c.x), fmaf(a.y, b.y, c.y));
}

#define MAXSWEEP 12
__global__ __launch_bounds__(256) void k_eigs(const float* __restrict__ Bc,
                                              const float* __restrict__ mu_arr,
                                              float* __restrict__ Eorb,
                                              float* __restrict__ ws_net,
                                              float* __restrict__ ws_rot) {
    int tid = threadIdx.x;
    int wave = tid >> 6, lane = tid & 63;
    int mat = blockIdx.x * 4 + wave;
    const float* colp = Bc + (size_t)mat * 4096 + (size_t)lane * 64;

    float2 W[32];
#pragma unroll
    for (int k = 0; k < 16; ++k) {
        float4 v = *reinterpret_cast<const float4*>(colp + 4 * k);
        W[2 * k + 0] = make_float2(v.x, v.y);
        W[2 * k + 1] = make_float2(v.z, v.w);
    }
    float mu = mu_arr[mat];

    float nrm = 0.f;
    int conv = 0;
    for (int sweep = 0; sweep < MAXSWEEP && !conv; ++sweep) {
        // fresh column norm (kills incremental drift)
        {
            float2 n0 = make_float2(0.f, 0.f), n1 = n0, n2 = n0, n3 = n0;
#pragma unroll
            for (int k = 0; k < 32; k += 4) {
                n0 = f2fma(W[k], W[k], n0);
                n1 = f2fma(W[k + 1], W[k + 1], n1);
                n2 = f2fma(W[k + 2], W[k + 2], n2);
                n3 = f2fma(W[k + 3], W[k + 3], n3);
            }
            nrm = ((n0.x + n0.y) + (n1.x + n1.y)) + ((n2.x + n2.y) + (n3.x + n3.y));
        }
        float biggest = 0.f;
        for (int m = 1; m < 64; ++m) {
            float pnrm = __shfl_xor(nrm, m, 64);
            float2 PW[32];
#pragma unroll
            for (int k = 0; k < 32; ++k) {
                PW[k].x = __shfl_xor(W[k].x, m, 64);
                PW[k].y = __shfl_xor(W[k].y, m, 64);
            }
            float2 d0 = make_float2(0.f, 0.f), d1 = d0, d2 = d0, d3 = d0;
#pragma unroll
            for (int k = 0; k < 32; k += 4) {
                d0 = f2fma(W[k], PW[k], d0);
                d1 = f2fma(W[k + 1], PW[k + 1], d1);
                d2 = f2fma(W[k + 2], PW[k + 2], d2);
                d3 = f2fma(W[k + 3], PW[k + 3], d3);
            }
            float g = ((d0.x + d0.y) + (d1.x + d1.y)) + ((d2.x + d2.y) + (d3.x + d3.y));
            bool isP = lane < (lane ^ m);
            float a = isP ? nrm : pnrm;
            float b = isP ? pnrm : nrm;
            float g2 = g * g;
            biggest = fmaxf(biggest, g2 * __builtin_amdgcn_rcpf(fmaxf(a * b, 1e-37f)));
            // rotation annihilating g:  t = sign(th)/(|th|+sqrt(th^2+1)), th=(b-a)/(2g)
            float gs = copysignf(fmaxf(fabsf(g), 1e-30f), g);
            float theta = (b - a) * (0.5f * __builtin_amdgcn_rcpf(gs));
            float t = copysignf(
                __builtin_amdgcn_rcpf(fabsf(theta) + sqrtf(fmaf(theta, theta, 1.f))), theta);
            t = (g2 > 1e-60f) ? t : 0.f;          // no rotation on zero coupling
            float c = __frsqrt_rn(fmaf(t, t, 1.f));
            float s = t * c;
            // exact Gram-diagonal update: a' = a - t*g ; b' = b + t*g
            nrm = isP ? fmaf(-t, g, a) : fmaf(t, g, b);
            float sp = isP ? -s : s;
#pragma unroll
            for (int k = 0; k < 32; ++k) {
                W[k].x = fmaf(sp, PW[k].x, c * W[k].x);
                W[k].y = fmaf(sp, PW[k].y, c * W[k].y);
            }
        }
#pragma unroll
        for (int off = 32; off > 0; off >>= 1)
            biggest = fmaxf(biggest, __shfl_xor(biggest, off, 64));
        conv = (biggest < 1e-6f);
    }

    // ---- extraction: lamB = ||w||, v = w/||w||, lamA = lamB - mu ----
    float l2;
    {
        float2 n0 = make_float2(0.f, 0.f), n1 = n0, n2 = n0, n3 = n0;
#pragma unroll
        for (int k = 0; k < 32; k += 4) {
            n0 = f2fma(W[k], W[k], n0);
            n1 = f2fma(W[k + 1], W[k + 1], n1);
            n2 = f2fma(W[k + 2], W[k + 2], n2);
            n3 = f2fma(W[k + 3], W[k + 3], n3);
        }
        l2 = ((n0.x + n0.y) + (n1.x + n1.y)) + ((n2.x + n2.y) + (n3.x + n3.y));
    }
    float lamB = sqrtf(l2);
    float lamA = lamB - mu;

    int rnk = 0;
    for (int j = 0; j < BD; ++j) {
        float lj = __shfl(lamA, j, 64);
        rnk += (lj < lamA) || (lj == lamA && j < lane);
    }
    Eorb[(size_t)mat * BD + rnk] = lamA;

    if (rnk < 32) {
        float inv = 1.f / lamB;
        float* vb = ((mat < VSPLIT) ? (ws_net + (size_t)mat * 2048)
                                    : (ws_rot + (size_t)(mat - VSPLIT) * 2048)) + (size_t)rnk * 64;
#pragma unroll
        for (int k = 0; k < 16; ++k) {
            float4 v4 = make_float4(W[2 * k].x * inv, W[2 * k].y * inv,
                                    W[2 * k + 1].x * inv, W[2 * k + 1].y * inv);
            *reinterpret_cast<float4*>(&vb[4 * k]) = v4;
        }
    }
}

// ---------------- stage 6: orb = P@Vocc, rho = 2*orb@orb^T, ener1 -----------
__global__ __launch_bounds__(256) void k_post(const float* __restrict__ phiS,
                                              const float* __restrict__ ws_net,
                                              const float* __restrict__ ws_rot,
                                              const float* __restrict__ Hws,
                                              float* __restrict__ rho_out,
                                              float* __restrict__ Eelec) {
    __shared__ float Pl[BD * PITCH];
    __shared__ float Vo[BD * 33];
    __shared__ float Orb[BD * 33];
    __shared__ float red[256];

    int mat = blockIdx.x, tid = threadIdx.x;
    size_t base = (size_t)mat * BD * BD;
    const float* vbase = (mat < VSPLIT) ? (ws_net + (size_t)mat * 2048)
                                        : (ws_rot + (size_t)(mat - VSPLIT) * 2048);
#pragma unroll
    for (int u = 0; u < 16; ++u) {
        int idx = tid + 256 * u; int i = idx >> 6, j = idx & 63;
        Pl[i * PITCH + j] = phiS[base + idx];
    }
#pragma unroll
    for (int u = 0; u < 8; ++u) {
        int idx = tid + 256 * u;          // 0..2047 — Vocc is [col][row]
        int c = idx >> 6, k = idx & 63;
        Vo[k * 33 + c] = vbase[idx];
    }
    __syncthreads();

    // Orb[i][r] = sum_k Pl[i][k] * Vo[k][r]
    {
        int i = tid >> 2, r0 = (tid & 3) * 8;
        float acc0=0,acc1=0,acc2=0,acc3=0,acc4=0,acc5=0,acc6=0,acc7=0;
        for (int k = 0; k < BD; ++k) {
            float pv = Pl[i * PITCH + k];
            acc0 += pv * Vo[k*33 + r0+0]; acc1 += pv * Vo[k*33 + r0+1];
            acc2 += pv * Vo[k*33 + r0+2]; acc3 += pv * Vo[k*33 + r0+3];
            acc4 += pv * Vo[k*33 + r0+4]; acc5 += pv * Vo[k*33 + r0+5];
            acc6 += pv * Vo[k*33 + r0+6]; acc7 += pv * Vo[k*33 + r0+7];
        }
        Orb[i*33 + r0+0]=acc0; Orb[i*33 + r0+1]=acc1; Orb[i*33 + r0+2]=acc2; Orb[i*33 + r0+3]=acc3;
        Orb[i*33 + r0+4]=acc4; Orb[i*33 + r0+5]=acc5; Orb[i*33 + r0+6]=acc6; Orb[i*33 + r0+7]=acc7;
    }
    __syncthreads();

    // rho = 2*Orb@Orb^T (K=32), 4x4 tile per thread; ener1 = sum(rho*H)
    float accE = 0.f;
    {
        int ti = tid >> 4, tj = tid & 15;
        int i0 = ti * 4, j0 = tj * 4;
        float a[4][4];
#pragma unroll
        for (int u = 0; u < 4; ++u)
#pragma unroll
            for (int v = 0; v < 4; ++v) a[u][v] = 0.f;
        for (int r = 0; r < 32; ++r) {
            float o0 = Orb[(i0+0)*33 + r], o1 = Orb[(i0+1)*33 + r];
            float o2 = Orb[(i0+2)*33 + r], o3 = Orb[(i0+3)*33 + r];
            float q0 = Orb[(j0+0)*33 + r], q1 = Orb[(j0+1)*33 + r];
            float q2 = Orb[(j0+2)*33 + r], q3 = Orb[(j0+3)*33 + r];
            a[0][0]+=o0*q0; a[0][1]+=o0*q1; a[0][2]+=o0*q2; a[0][3]+=o0*q3;
            a[1][0]+=o1*q0; a[1][1]+=o1*q1; a[1][2]+=o1*q2; a[1][3]+=o1*q3;
            a[2][0]+=o2*q0; a[2][1]+=o2*q1; a[2][2]+=o2*q2; a[2][3]+=o2*q3;
            a[3][0]+=o3*q0; a[3][1]+=o3*q1; a[3][2]+=o3*q2; a[3][3]+=o3*q3;
        }
#pragma unroll
        for (int u = 0; u < 4; ++u) {
            float4 rv;
            rv.x = 2.f*a[u][0]; rv.y = 2.f*a[u][1]; rv.z = 2.f*a[u][2]; rv.w = 2.f*a[u][3];
            size_t off = base + (size_t)(i0+u) * BD + j0;
            *reinterpret_cast<float4*>(&rho_out[off]) = rv;
            const float4 hv = *reinterpret_cast<const float4*>(&Hws[off]);
            accE += rv.x*hv.x + rv.y*hv.y + rv.z*hv.z + rv.w*hv.w;
        }
    }
    red[tid] = accE;
    __syncthreads();
    for (int st = 128; st > 0; st >>= 1) { if (tid < st) red[tid] += red[tid + st]; __syncthreads(); }
    if (tid == 0) Eelec[mat] = Eelec[mat] + red[0];
}

// ---------------- launcher ----------------
extern "C" void kernel_launch(void* const* d_in, const int* in_sizes, int n_in,
                              void* d_out, int out_size, void* d_ws, size_t ws_size,
                              hipStream_t stream) {
    const float* x           = (const float*)d_in[0];
    const float* net_base    = (const float*)d_in[1];
    const float* rot_tensors = (const float*)d_in[2];
    const float* S           = (const float*)d_in[3];
    const float* G           = (const float*)d_in[4];
    const float* rho_in      = (const float*)d_in[5];
    const float* phiS        = (const float*)d_in[6];
    const float* qn          = (const float*)d_in[7];
    // d_in[8] occ_mask: constant (col < 32), folded into k_eigs/k_post
    const int* scatter_idx   = (const int*)d_in[9];
    const int* rot_gather    = (const int*)d_in[10];
    const int* oper_gather   = (const int*)d_in[11];
    const int* rep_gather    = (const int*)d_in[12];
    const int* rep_seg       = (const int*)d_in[13];

    float* out   = (float*)d_out;
    float* oEelec = out;                               // NMOL
    float* oErep  = oEelec + NMOL;                     // NMOL
    float* oEorb  = oErep + NMOL;                      // NMOL*64
    float* oRho   = oEorb + (size_t)NMOL * BD;         // NMOL*64*64 (scratch Bc before k_post)
    float* oF     = oRho + (size_t)NMOL * BD * BD;     // NMOL*64*64

    // workspace layout (~61.6 MB):
    float* ws_net = (float*)d_ws;                      // NN floats (Vocc reuse after k_erep)
    float* ws_rot = ws_net + NN;                       // 3,000,004 floats (Vocc spill + mu)
    float* ws_H   = ws_rot + 3000004;                  // NMOL*64*64 floats
    int*   winner = (int*)ws_H;                        // alias (dead before H is written)
    float* ws_mu  = ws_rot + 2800000;                  // 2048 floats (after rot_out dead)

    int nx = in_sizes[0];
    int total_ops = NMOL * BD * BD;

    k_copy<<<2048, 256, 0, stream>>>((const float4*)net_base, (float4*)ws_net, NN / 4);
    int gb = (nx + 255) / 256;
    k_scat_init <<<gb, 256, 0, stream>>>(scatter_idx, winner, nx);
    k_scat_max  <<<gb, 256, 0, stream>>>(scatter_idx, winner, nx);
    k_scat_write<<<gb, 256, 0, stream>>>(scatter_idx, winner, x, ws_net, nx);
    k_rot<<<(NROT_C + 255) / 256, 256, 0, stream>>>(ws_net, rot_gather, rot_tensors, ws_rot, NROT_C);
    k_oper<<<(total_ops + 255) / 256, 256, 0, stream>>>(ws_rot, oper_gather, ws_H, total_ops);
    k_fock<<<NMOL, 256, 0, stream>>>(S, G, rho_in, qn, ws_H, oF, oEelec);
    // Erep BEFORE k_eigs (Vocc overwrites ws_net/ws_rot)
    k_erep<<<NMOL, 64, 0, stream>>>(ws_net, rep_gather, rep_seg, oErep, NREP_C);
    k_prep<<<NMOL, 256, 0, stream>>>(oF, phiS, oRho /*Bc scratch*/, ws_mu);
    k_eigs<<<NMOL / 4, 256, 0, stream>>>(oRho, ws_mu, oEorb, ws_net, ws_rot);
    k_post<<<NMOL, 256, 0, stream>>>(phiS, ws_net, ws_rot, ws_H, oRho, oEelec);
}

// Round 5
// 923.064 us; speedup vs baseline: 6.5338x; 1.1355x over previous
//
#include <hip/hip_runtime.h>

// ---------------- problem constants (match reference) ----------------
#define NMOL   2048
#define BD     64
#define PITCH  65            // LDS row pitch for k_fock/k_post
#define PP2    68            // k_prep pitch: 16B-aligned rows
#define NROT_C 1000000
#define NN     4000000       // len(net_vals)
#define NREP_C 500000
#define VSPLIT 1953          // Vocc for mat<VSPLIT lives in ws_net, rest in ws_rot

// ---------------- stage 1: net_vals = net_base; scatter x (last write wins) --
__global__ __launch_bounds__(256) void k_copy(const float4* __restrict__ src,
                                              float4* __restrict__ dst, int n4) {
    int i = blockIdx.x * blockDim.x + threadIdx.x;
    int stride = gridDim.x * blockDim.x;
    for (; i < n4; i += stride) dst[i] = src[i];
}

__global__ __launch_bounds__(256) void k_scat_init(const int* __restrict__ idx,
                                                   int* __restrict__ winner, int nx) {
    int i = blockIdx.x * blockDim.x + threadIdx.x;
    if (i < nx) winner[idx[i]] = -1;
}
__global__ __launch_bounds__(256) void k_scat_max(const int* __restrict__ idx,
                                                  int* __restrict__ winner, int nx) {
    int i = blockIdx.x * blockDim.x + threadIdx.x;
    if (i < nx) atomicMax(&winner[idx[i]], i);
}
__global__ __launch_bounds__(256) void k_scat_write(const int* __restrict__ idx,
                                                    const int* __restrict__ winner,
                                                    const float* __restrict__ x,
                                                    float* __restrict__ net, int nx) {
    int i = blockIdx.x * blockDim.x + threadIdx.x;
    if (i < nx && winner[idx[i]] == i) net[idx[i]] = x[i];
}

// ---------------- stage 2: rotations + oper gather ----------------
__global__ __launch_bounds__(256) void k_rot(const float* __restrict__ net,
                                             const int* __restrict__ rg,
                                             const float* __restrict__ rt,
                                             float* __restrict__ rot_out, int nrot) {
    int r = blockIdx.x * blockDim.x + threadIdx.x;
    if (r == 0) { rot_out[0] = 0.f; rot_out[1] = 1.f; }
    if (r >= nrot) return;
    int i0 = rg[3 * r], i1 = rg[3 * r + 1], i2 = rg[3 * r + 2];
    float v0 = net[i0], v1 = net[i1], v2 = net[i2];
    const float* T = rt + (size_t)r * 9;
    rot_out[2 + 3 * r + 0] = T[0] * v0 + T[1] * v1 + T[2] * v2;
    rot_out[2 + 3 * r + 1] = T[3] * v0 + T[4] * v1 + T[5] * v2;
    rot_out[2 + 3 * r + 2] = T[6] * v0 + T[7] * v1 + T[8] * v2;
}

__global__ __launch_bounds__(256) void k_oper(const float* __restrict__ rot_out,
                                              const int* __restrict__ og,
                                              float* __restrict__ H, int total) {
    int i = blockIdx.x * blockDim.x + threadIdx.x;
    if (i < total) H[i] = rot_out[og[i]];
}

// ---------------- stage 3: Fock assembly, one block per molecule ------------
__global__ __launch_bounds__(256) void k_fock(const float* __restrict__ S,
                                              const float* __restrict__ G,
                                              const float* __restrict__ rho,
                                              const float* __restrict__ qn,
                                              const float* __restrict__ H,
                                              float* __restrict__ F,
                                              float* __restrict__ Eelec) {
    __shared__ float Ssh[BD * PITCH];
    __shared__ float part[BD * 4];
    __shared__ float dQ[BD], ep[BD];
    int m = blockIdx.x, tid = threadIdx.x;
    size_t base = (size_t)m * BD * BD;
    int i = tid >> 2, jq = tid & 3;
    int j0 = jq * 16;

    float acc = 0.f;
#pragma unroll
    for (int jj = 0; jj < 16; ++jj) {
        int j = j0 + jj;
        float sv = S[base + i * BD + j];
        float rv = rho[base + i * BD + j];
        Ssh[i * PITCH + j] = sv;
        acc += sv * rv;
    }
    part[i * 4 + jq] = acc;
    __syncthreads();
    if (tid < BD)
        dQ[tid] = qn[(size_t)m * BD + tid] -
                  (part[tid * 4] + part[tid * 4 + 1] + part[tid * 4 + 2] + part[tid * 4 + 3]);
    __syncthreads();

    float acc2 = 0.f;
#pragma unroll
    for (int jj = 0; jj < 16; ++jj) {
        int j = j0 + jj;
        acc2 += G[base + i * BD + j] * dQ[j];
    }
    part[i * 4 + jq] = acc2;
    __syncthreads();
    if (tid < BD) {
        float e = part[tid * 4] + part[tid * 4 + 1] + part[tid * 4 + 2] + part[tid * 4 + 3];
        ep[tid] = e;
        float v = dQ[tid] * e;
        for (int off = 32; off > 0; off >>= 1) v += __shfl_down(v, off, 64);
        if (tid == 0) Eelec[m] = 0.5f * v;      // ener2; k_post adds ener1 later
    }
    __syncthreads();

#pragma unroll
    for (int u = 0; u < 16; ++u) {
        int idx = tid + 256 * u;
        int i2 = idx >> 6, j2 = idx & 63;
        F[base + idx] = H[base + idx] - 0.5f * Ssh[i2 * PITCH + j2] * (ep[i2] + ep[j2]);
    }
}

// ---------------- stage 4: Erep segment sum (deterministic, no atomics) -----
__global__ __launch_bounds__(64) void k_erep(const float* __restrict__ net,
                                             const int* __restrict__ rg,
                                             const int* __restrict__ seg,
                                             float* __restrict__ Erep, int nrep) {
    int m = blockIdx.x, lane = threadIdx.x;
    int lo = 0, hi = nrep;
    while (lo < hi) { int mid = (lo + hi) >> 1; if (seg[mid] < m) lo = mid + 1; else hi = mid; }
    int start = lo;
    hi = nrep;
    while (lo < hi) { int mid = (lo + hi) >> 1; if (seg[mid] < m + 1) lo = mid + 1; else hi = mid; }
    int end = lo;
    float s = 0.f;
    for (int k = start + lane; k < end; k += 64) s += net[rg[k]];
    for (int off = 32; off > 0; off >>= 1) s += __shfl_down(s, off, 64);
    if (lane == 0) Erep[m] = s;
}

// ---------------- stage 5a: k_prep — B = sym(P^T F P) + mu*I ----------------
__global__ __launch_bounds__(256) void k_prep(const float* __restrict__ F,
                                              const float* __restrict__ phiS,
                                              float* __restrict__ Bc,
                                              float* __restrict__ mu_out) {
    __shared__ float Ft[BD * PP2];   // F^T, later fockp
    __shared__ float PL[BD * PP2];   // phiS row-major
    __shared__ float XL[BD * PP2];   // F @ P
    __shared__ float rs[BD];
    __shared__ float s_mu;
    int mat = blockIdx.x, tid = threadIdx.x;
    size_t base = (size_t)mat * BD * BD;

#pragma unroll
    for (int u = 0; u < 16; ++u) {
        int idx = tid + 256 * u; int r = idx >> 6, c = idx & 63;
        Ft[c * PP2 + r] = F[base + idx];
        PL[r * PP2 + c] = phiS[base + idx];
    }
    __syncthreads();

    int ti = tid >> 4, tj = tid & 15;
    int i0 = ti * 4, j0 = tj * 4;

    // XL = F @ P
    {
        float a[4][4];
#pragma unroll
        for (int u = 0; u < 4; ++u)
#pragma unroll
            for (int v = 0; v < 4; ++v) a[u][v] = 0.f;
        for (int k = 0; k < BD; ++k) {
            float4 av = *reinterpret_cast<const float4*>(&Ft[k * PP2 + i0]);
            float4 bv = *reinterpret_cast<const float4*>(&PL[k * PP2 + j0]);
            a[0][0] += av.x*bv.x; a[0][1] += av.x*bv.y; a[0][2] += av.x*bv.z; a[0][3] += av.x*bv.w;
            a[1][0] += av.y*bv.x; a[1][1] += av.y*bv.y; a[1][2] += av.y*bv.z; a[1][3] += av.y*bv.w;
            a[2][0] += av.z*bv.x; a[2][1] += av.z*bv.y; a[2][2] += av.z*bv.z; a[2][3] += av.z*bv.w;
            a[3][0] += av.w*bv.x; a[3][1] += av.w*bv.y; a[3][2] += av.w*bv.z; a[3][3] += av.w*bv.w;
        }
#pragma unroll
        for (int u = 0; u < 4; ++u)
            *reinterpret_cast<float4*>(&XL[(i0 + u) * PP2 + j0]) =
                make_float4(a[u][0], a[u][1], a[u][2], a[u][3]);
    }
    __syncthreads();

    // Ft = P^T @ XL  (fockp; overwrites F^T)
    {
        float a[4][4];
#pragma unroll
        for (int u = 0; u < 4; ++u)
#pragma unroll
            for (int v = 0; v < 4; ++v) a[u][v] = 0.f;
        for (int k = 0; k < BD; ++k) {
            float4 av = *reinterpret_cast<const float4*>(&PL[k * PP2 + i0]);
            float4 bv = *reinterpret_cast<const float4*>(&XL[k * PP2 + j0]);
            a[0][0] += av.x*bv.x; a[0][1] += av.x*bv.y; a[0][2] += av.x*bv.z; a[0][3] += av.x*bv.w;
            a[1][0] += av.y*bv.x; a[1][1] += av.y*bv.y; a[1][2] += av.y*bv.z; a[1][3] += av.y*bv.w;
            a[2][0] += av.z*bv.x; a[2][1] += av.z*bv.y; a[2][2] += av.z*bv.z; a[2][3] += av.z*bv.w;
            a[3][0] += av.w*bv.x; a[3][1] += av.w*bv.y; a[3][2] += av.w*bv.z; a[3][3] += av.w*bv.w;
        }
        __syncthreads();
#pragma unroll
        for (int u = 0; u < 4; ++u)
            *reinterpret_cast<float4*>(&Ft[(i0 + u) * PP2 + j0]) =
                make_float4(a[u][0], a[u][1], a[u][2], a[u][3]);
    }
    __syncthreads();

    // Gershgorin row sums of sym(Ft)
    {
        int r = tid >> 2, part = tid & 3;
        float s = 0.f;
#pragma unroll
        for (int jj = 0; jj < 16; ++jj) {
            int j = part * 16 + jj;
            s += fabsf(0.5f * (Ft[r * PP2 + j] + Ft[j * PP2 + r]));
        }
        s += __shfl_xor(s, 1, 64);
        s += __shfl_xor(s, 2, 64);
        if (part == 0) rs[r] = s;
    }
    __syncthreads();
    if (tid < BD) {
        float v = rs[tid];
        for (int off = 32; off > 0; off >>= 1) v = fmaxf(v, __shfl_down(v, off, 64));
        if (tid == 0) { s_mu = 1.05f * v + 0.5f; mu_out[mat] = 1.05f * v + 0.5f; }
    }
    __syncthreads();

    // write B col-major (+mu on diag); symmetric so (c,r) orientation is free
    float mu = s_mu;
#pragma unroll
    for (int u = 0; u < 16; ++u) {
        int idx = tid + 256 * u; int c = idx >> 6, r = idx & 63;
        float v = 0.5f * (Ft[c * PP2 + r] + Ft[r * PP2 + c]);
        if (c == r) v += mu;
        Bc[base + idx] = v;
    }
}

// ---------------- stage 5b: k_eigs — BL/hypercube register Jacobi -----------
// Lane pair = processor p: lane 2p holds rows 0..31 of two columns (slots A,B),
// lane 2p+1 rows 32..63. The rotated pair is always the co-resident (A,B):
// dot = in-lane partial + one shfl_xor(1). Hypercube ordering: round m pairs
// (C_h(p), C_h(p)^m), h = msb(m), C_h(p) = insert-0-bit at h. Within a level
// only slot B moves: B <- shfl_xor(B, 2*(m^(m+1))). Level changes (5/sweep)
// rebuild both slots via bpermute pulls. Column identity is never needed.
#define MAXSWEEP 12
__global__ __launch_bounds__(256) void k_eigs(const float* __restrict__ Bc,
                                              const float* __restrict__ mu_arr,
                                              float* __restrict__ Eorb,
                                              float* __restrict__ ws_net,
                                              float* __restrict__ ws_rot) {
    int tid = threadIdx.x;
    int wave = tid >> 6, lane = tid & 63;
    int p  = lane >> 1;          // processor 0..31
    int hf = lane & 1;           // half: 0 = rows 0..31, 1 = rows 32..63
    int mat = blockIdx.x * 4 + wave;
    const float* basep = Bc + (size_t)mat * 4096;

    float A[32], B[32];
#pragma unroll
    for (int k = 0; k < 8; ++k) {
        float4 va = *reinterpret_cast<const float4*>(basep + (2 * p) * 64 + hf * 32 + 4 * k);
        float4 vb = *reinterpret_cast<const float4*>(basep + (2 * p + 1) * 64 + hf * 32 + 4 * k);
        A[4*k+0] = va.x; A[4*k+1] = va.y; A[4*k+2] = va.z; A[4*k+3] = va.w;
        B[4*k+0] = vb.x; B[4*k+1] = vb.y; B[4*k+2] = vb.z; B[4*k+3] = vb.w;
    }
    float mu = mu_arr[mat];

    float na = 0.f, nb = 0.f;
    int conv = 0;
    for (int sweep = 0; sweep < MAXSWEEP && !conv; ++sweep) {
        // fresh full-column norms (identical in both lanes of the pair)
        {
            float pa0 = 0.f, pa1 = 0.f, pb0 = 0.f, pb1 = 0.f;
#pragma unroll
            for (int k = 0; k < 32; k += 2) {
                pa0 = fmaf(A[k], A[k], pa0);     pa1 = fmaf(A[k+1], A[k+1], pa1);
                pb0 = fmaf(B[k], B[k], pb0);     pb1 = fmaf(B[k+1], B[k+1], pb1);
            }
            float pa = pa0 + pa1, pb = pb0 + pb1;
            na = pa + __shfl_xor(pa, 1, 64);
            nb = pb + __shfl_xor(pb, 1, 64);
        }
        float biggest = 0.f;
        for (int m = 1; m < 64; ++m) {
            // ---- rotate local pair (A,B) ----
            float d0 = 0.f, d1 = 0.f, d2 = 0.f, d3 = 0.f;
#pragma unroll
            for (int k = 0; k < 32; k += 4) {
                d0 = fmaf(A[k],   B[k],   d0);
                d1 = fmaf(A[k+1], B[k+1], d1);
                d2 = fmaf(A[k+2], B[k+2], d2);
                d3 = fmaf(A[k+3], B[k+3], d3);
            }
            float gp = (d0 + d1) + (d2 + d3);
            float g = gp + __shfl_xor(gp, 1, 64);
            float g2 = g * g;
            biggest = fmaxf(biggest, g2 * __builtin_amdgcn_rcpf(fmaxf(na * nb, 1e-37f)));
            float gs = copysignf(fmaxf(fabsf(g), 1e-30f), g);
            float theta = (nb - na) * (0.5f * __builtin_amdgcn_rcpf(gs));
            float t = copysignf(
                __builtin_amdgcn_rcpf(fabsf(theta) + sqrtf(fmaf(theta, theta, 1.f))), theta);
            t = (g2 > 1e-60f) ? t : 0.f;
            float c = __frsqrt_rn(fmaf(t, t, 1.f));
            float s = t * c;
            na = fmaf(-t, g, na);
            nb = fmaf( t, g, nb);
#pragma unroll
            for (int k = 0; k < 32; ++k) {
                float a = A[k], b = B[k];
                A[k] = fmaf(-s, b, c * a);
                B[k] = fmaf( s, a, c * b);
            }
            // ---- move columns for next round ----
            if (m < 63) {
                int mp = m + 1;
                if (mp & m) {
                    // same level: B <- B of proc p ^ (m^mp)
                    int xl = (m ^ mp) << 1;
#pragma unroll
                    for (int k = 0; k < 32; ++k) B[k] = __shfl_xor(B[k], xl, 64);
                    nb = __shfl_xor(nb, xl, 64);
                } else {
                    // level change: mp = 2^hn
                    int hn = 31 - __builtin_clz(mp);
                    int ho = hn - 1;
                    int cA = ((p >> hn) << (hn + 1)) | (p & ((1 << hn) - 1));
                    int cB = cA | mp;
                    int loA = (1 << ho) - 1;
                    int sAsl = (cA >> ho) & 1;
                    int xa = sAsl ? (cA ^ m) : cA;
                    int sApr = ((xa >> (ho + 1)) << ho) | (xa & loA);
                    int sBsl = (cB >> ho) & 1;
                    int xb = sBsl ? (cB ^ m) : cB;
                    int sBpr = ((xb >> (ho + 1)) << ho) | (xb & loA);
                    int laneA = 2 * sApr + hf, laneB = 2 * sBpr + hf;
                    float t0 = __shfl(na, laneA, 64), t1 = __shfl(nb, laneA, 64);
                    float t2 = __shfl(na, laneB, 64), t3 = __shfl(nb, laneB, 64);
                    float nna = sAsl ? t1 : t0;
                    float nnb = sBsl ? t3 : t2;
#pragma unroll
                    for (int k = 0; k < 32; ++k) {
                        float a0 = __shfl(A[k], laneA, 64);
                        float a1 = __shfl(B[k], laneA, 64);
                        float b0 = __shfl(A[k], laneB, 64);
                        float b1 = __shfl(B[k], laneB, 64);
                        A[k] = sAsl ? a1 : a0;
                        B[k] = sBsl ? b1 : b0;
                    }
                    na = nna; nb = nnb;
                }
            }
        }
#pragma unroll
        for (int off = 2; off <= 32; off <<= 1)
            biggest = fmaxf(biggest, __shfl_xor(biggest, off, 64));
        conv = (biggest < 1e-6f);
    }

    // ---- extraction ----
    float pa = 0.f, pb = 0.f;
#pragma unroll
    for (int k = 0; k < 32; ++k) { pa = fmaf(A[k], A[k], pa); pb = fmaf(B[k], B[k], pb); }
    float la2 = pa + __shfl_xor(pa, 1, 64);
    float lb2 = pb + __shfl_xor(pb, 1, 64);
    float lamBA = sqrtf(la2), lamBB = sqrtf(lb2);
    float lA = lamBA - mu, lB = lamBB - mu;
    int idA = 2 * p, idB = 2 * p + 1;
    int rnkA = 0, rnkB = 0;
    for (int j = 0; j < 32; ++j) {
        float va = __shfl(lA, 2 * j, 64);
        float vb = __shfl(lB, 2 * j + 1, 64);
        int ja = 2 * j, jb = 2 * j + 1;
        rnkA += (va < lA) || (va == lA && ja < idA);
        rnkA += (vb < lA) || (vb == lA && jb < idA);
        rnkB += (va < lB) || (va == lB && ja < idB);
        rnkB += (vb < lB) || (vb == lB && jb < idB);
    }
    if (hf == 0) Eorb[(size_t)mat * BD + rnkA] = lA;
    else         Eorb[(size_t)mat * BD + rnkB] = lB;

    float* vb_ = (mat < VSPLIT) ? (ws_net + (size_t)mat * 2048)
                                : (ws_rot + (size_t)(mat - VSPLIT) * 2048);
    if (rnkA < 32) {
        float inv = 1.f / lamBA;
        float* dst = vb_ + (size_t)rnkA * 64 + hf * 32;
#pragma unroll
        for (int k = 0; k < 8; ++k)
            *reinterpret_cast<float4*>(&dst[4 * k]) =
                make_float4(A[4*k] * inv, A[4*k+1] * inv, A[4*k+2] * inv, A[4*k+3] * inv);
    }
    if (rnkB < 32) {
        float inv = 1.f / lamBB;
        float* dst = vb_ + (size_t)rnkB * 64 + hf * 32;
#pragma unroll
        for (int k = 0; k < 8; ++k)
            *reinterpret_cast<float4*>(&dst[4 * k]) =
                make_float4(B[4*k] * inv, B[4*k+1] * inv, B[4*k+2] * inv, B[4*k+3] * inv);
    }
}

// ---------------- stage 6: orb = P@Vocc, rho = 2*orb@orb^T, ener1 -----------
__global__ __launch_bounds__(256) void k_post(const float* __restrict__ phiS,
                                              const float* __restrict__ ws_net,
                                              const float* __restrict__ ws_rot,
                                              const float* __restrict__ Hws,
                                              float* __restrict__ rho_out,
                                              float* __restrict__ Eelec) {
    __shared__ float Pl[BD * PITCH];
    __shared__ float Vo[BD * 33];
    __shared__ float Orb[BD * 33];
    __shared__ float red[256];

    int mat = blockIdx.x, tid = threadIdx.x;
    size_t base = (size_t)mat * BD * BD;
    const float* vbase = (mat < VSPLIT) ? (ws_net + (size_t)mat * 2048)
                                        : (ws_rot + (size_t)(mat - VSPLIT) * 2048);
#pragma unroll
    for (int u = 0; u < 16; ++u) {
        int idx = tid + 256 * u; int i = idx >> 6, j = idx & 63;
        Pl[i * PITCH + j] = phiS[base + idx];
    }
#pragma unroll
    for (int u = 0; u < 8; ++u) {
        int idx = tid + 256 * u;          // 0..2047 — Vocc is [rank][row]
        int c = idx >> 6, k = idx & 63;
        Vo[k * 33 + c] = vbase[idx];
    }
    __syncthreads();

    // Orb[i][r] = sum_k Pl[i][k] * Vo[k][r]
    {
        int i = tid >> 2, r0 = (tid & 3) * 8;
        float acc0=0,acc1=0,acc2=0,acc3=0,acc4=0,acc5=0,acc6=0,acc7=0;
        for (int k = 0; k < BD; ++k) {
            float pv = Pl[i * PITCH + k];
            acc0 += pv * Vo[k*33 + r0+0]; acc1 += pv * Vo[k*33 + r0+1];
            acc2 += pv * Vo[k*33 + r0+2]; acc3 += pv * Vo[k*33 + r0+3];
            acc4 += pv * Vo[k*33 + r0+4]; acc5 += pv * Vo[k*33 + r0+5];
            acc6 += pv * Vo[k*33 + r0+6]; acc7 += pv * Vo[k*33 + r0+7];
        }
        Orb[i*33 + r0+0]=acc0; Orb[i*33 + r0+1]=acc1; Orb[i*33 + r0+2]=acc2; Orb[i*33 + r0+3]=acc3;
        Orb[i*33 + r0+4]=acc4; Orb[i*33 + r0+5]=acc5; Orb[i*33 + r0+6]=acc6; Orb[i*33 + r0+7]=acc7;
    }
    __syncthreads();

    // rho = 2*Orb@Orb^T (K=32), 4x4 tile per thread; ener1 = sum(rho*H)
    float accE = 0.f;
    {
        int ti = tid >> 4, tj = tid & 15;
        int i0 = ti * 4, j0 = tj * 4;
        float a[4][4];
#pragma unroll
        for (int u = 0; u < 4; ++u)
#pragma unroll
            for (int v = 0; v < 4; ++v) a[u][v] = 0.f;
        for (int r = 0; r < 32; ++r) {
            float o0 = Orb[(i0+0)*33 + r], o1 = Orb[(i0+1)*33 + r];
            float o2 = Orb[(i0+2)*33 + r], o3 = Orb[(i0+3)*33 + r];
            float q0 = Orb[(j0+0)*33 + r], q1 = Orb[(j0+1)*33 + r];
            float q2 = Orb[(j0+2)*33 + r], q3 = Orb[(j0+3)*33 + r];
            a[0][0]+=o0*q0; a[0][1]+=o0*q1; a[0][2]+=o0*q2; a[0][3]+=o0*q3;
            a[1][0]+=o1*q0; a[1][1]+=o1*q1; a[1][2]+=o1*q2; a[1][3]+=o1*q3;
            a[2][0]+=o2*q0; a[2][1]+=o2*q1; a[2][2]+=o2*q2; a[2][3]+=o2*q3;
            a[3][0]+=o3*q0; a[3][1]+=o3*q1; a[3][2]+=o3*q2; a[3][3]+=o3*q3;
        }
#pragma unroll
        for (int u = 0; u < 4; ++u) {
            float4 rv;
            rv.x = 2.f*a[u][0]; rv.y = 2.f*a[u][1]; rv.z = 2.f*a[u][2]; rv.w = 2.f*a[u][3];
            size_t off = base + (size_t)(i0+u) * BD + j0;
            *reinterpret_cast<float4*>(&rho_out[off]) = rv;
            const float4 hv = *reinterpret_cast<const float4*>(&Hws[off]);
            accE += rv.x*hv.x + rv.y*hv.y + rv.z*hv.z + rv.w*hv.w;
        }
    }
    red[tid] = accE;
    __syncthreads();
    for (int st = 128; st > 0; st >>= 1) { if (tid < st) red[tid] += red[tid + st]; __syncthreads(); }
    if (tid == 0) Eelec[mat] = Eelec[mat] + red[0];
}

// ---------------- launcher ----------------
extern "C" void kernel_launch(void* const* d_in, const int* in_sizes, int n_in,
                              void* d_out, int out_size, void* d_ws, size_t ws_size,
                              hipStream_t stream) {
    const float* x           = (const float*)d_in[0];
    const float* net_base    = (const float*)d_in[1];
    const float* rot_tensors = (const float*)d_in[2];
    const float* S           = (const float*)d_in[3];
    const float* G           = (const float*)d_in[4];
    const float* rho_in      = (const float*)d_in[5];
    const float* phiS        = (const float*)d_in[6];
    const float* qn          = (const float*)d_in[7];
    // d_in[8] occ_mask: constant (col < 32), folded into k_eigs/k_post
    const int* scatter_idx   = (const int*)d_in[9];
    const int* rot_gather    = (const int*)d_in[10];
    const int* oper_gather   = (const int*)d_in[11];
    const int* rep_gather    = (const int*)d_in[12];
    const int* rep_seg       = (const int*)d_in[13];

    float* out   = (float*)d_out;
    float* oEelec = out;                               // NMOL
    float* oErep  = oEelec + NMOL;                     // NMOL
    float* oEorb  = oErep + NMOL;                      // NMOL*64
    float* oRho   = oEorb + (size_t)NMOL * BD;         // NMOL*64*64 (scratch Bc before k_post)
    float* oF     = oRho + (size_t)NMOL * BD * BD;     // NMOL*64*64

    // workspace layout (~61.6 MB):
    float* ws_net = (float*)d_ws;                      // NN floats (Vocc reuse after k_erep)
    float* ws_rot = ws_net + NN;                       // 3,000,004 floats (Vocc spill + mu)
    float* ws_H   = ws_rot + 3000004;                  // NMOL*64*64 floats
    int*   winner = (int*)ws_H;                        // alias (dead before H is written)
    float* ws_mu  = ws_rot + 2800000;                  // 2048 floats (after rot_out dead)

    int nx = in_sizes[0];
    int total_ops = NMOL * BD * BD;

    k_copy<<<2048, 256, 0, stream>>>((const float4*)net_base, (float4*)ws_net, NN / 4);
    int gb = (nx + 255) / 256;
    k_scat_init <<<gb, 256, 0, stream>>>(scatter_idx, winner, nx);
    k_scat_max  <<<gb, 256, 0, stream>>>(scatter_idx, winner, nx);
    k_scat_write<<<gb, 256, 0, stream>>>(scatter_idx, winner, x, ws_net, nx);
    k_rot<<<(NROT_C + 255) / 256, 256, 0, stream>>>(ws_net, rot_gather, rot_tensors, ws_rot, NROT_C);
    k_oper<<<(total_ops + 255) / 256, 256, 0, stream>>>(ws_rot, oper_gather, ws_H, total_ops);
    k_fock<<<NMOL, 256, 0, stream>>>(S, G, rho_in, qn, ws_H, oF, oEelec);
    // Erep BEFORE k_eigs (Vocc overwrites ws_net/ws_rot)
    k_erep<<<NMOL, 64, 0, stream>>>(ws_net, rep_gather, rep_seg, oErep, NREP_C);
    k_prep<<<NMOL, 256, 0, stream>>>(oF, phiS, oRho /*Bc scratch*/, ws_mu);
    k_eigs<<<NMOL / 4, 256, 0, stream>>>(oRho, ws_mu, oEorb, ws_net, ws_rot);
    k_post<<<NMOL, 256, 0, stream>>>(phiS, ws_net, ws_rot, ws_H, oRho, oEelec);
}